// Round 1
// baseline (213.445 us; speedup 1.0000x reference)
//
#include <hip/hip_runtime.h>

// Problem constants
#define HW    16384   // 128*128
#define WIDTH 128

// ws float offsets
#define OFF_WFEAT 0        // [64][96]  fused weight: j<32 -> WL, j>=32 -> WVV
#define OFF_BFEAT 6144     // [96]      fused bias for valid positions
#define OFF_LPAD  6240     // [32]      logit constant for padded window slots
#define OFF_VPAD  6272     // [64]      V constant for padded window slots
#define OFF_LV    6400     // [8][96][16384] per-pixel features (feature-major)

// ---------------------------------------------------------------------------
// K0: fold all weight matrices (tiny, one block)
// ---------------------------------------------------------------------------
__global__ __launch_bounds__(256) void k0_fuse(
    const float* __restrict__ up_query,
    const float* __restrict__ Wk, const float* __restrict__ bk,
    const float* __restrict__ Wv, const float* __restrict__ bv,
    const float* __restrict__ Wq, const float* __restrict__ bq,
    const float* __restrict__ Wka, const float* __restrict__ bka,
    const float* __restrict__ Wva, const float* __restrict__ bva,
    float* __restrict__ ws)
{
    __shared__ float qc[4][64];     // q_const[q][f] = up_query@Wq + bq
    __shared__ float bkW[64];       // bk @ Wka
    __shared__ float bvW[64];       // bv @ Wva
    __shared__ float WKK[64][64];   // Wk @ Wka

    const int tid = threadIdx.x;

    // P1: q_const (256 jobs)
    {
        int q = tid >> 6, f = tid & 63;
        float a = bq[f];
        for (int c = 0; c < 64; ++c) a = fmaf(up_query[q*64+c], Wq[c*64+f], a);
        qc[q][f] = a;
    }
    // P2: bias projections
    if (tid < 64) {
        float a = 0.f, v = 0.f;
        for (int e = 0; e < 64; ++e) {
            a = fmaf(bk[e], Wka[e*64+tid], a);
            v = fmaf(bv[e], Wva[e*64+tid], v);
        }
        bkW[tid] = a; bvW[tid] = v;
    }
    __syncthreads();

    // P3: WKK (to LDS) and WVV (straight to ws)
    for (int i = tid; i < 4096; i += 256) {
        int c = i >> 6, f = i & 63;
        float a = 0.f, v = 0.f;
        for (int e = 0; e < 64; ++e) {
            a = fmaf(Wk[c*64+e], Wka[e*64+f], a);
            v = fmaf(Wv[c*64+e], Wva[e*64+f], v);
        }
        WKK[c][f] = a;
        ws[OFF_WFEAT + c*96 + 32 + f] = v;
    }
    __syncthreads();

    const float rs = 0.35355339059327373f; // 1/sqrt(8)

    // P4: WL[c][hq] = rs * sum_d WKK[c][h*8+d] * qc[q][h*8+d]
    for (int i = tid; i < 2048; i += 256) {
        int c = i >> 5, hq = i & 31;
        int h = hq >> 2, q = hq & 3;
        float a = 0.f;
        for (int d = 0; d < 8; ++d) a = fmaf(WKK[c][h*8+d], qc[q][h*8+d], a);
        ws[OFF_WFEAT + c*96 + hq] = a * rs;
    }
    // P5: logit biases (valid: 2*bk@Wka + bka ; padded: bk@Wka + bka)
    if (tid < 32) {
        int h = tid >> 2, q = tid & 3;
        float av = 0.f, ap = 0.f;
        for (int d = 0; d < 8; ++d) {
            int f = h*8 + d;
            av = fmaf(2.f*bkW[f] + bka[f], qc[q][f], av);
            ap = fmaf(bkW[f] + bka[f], qc[q][f], ap);
        }
        ws[OFF_BFEAT + tid] = av * rs;
        ws[OFF_LPAD + tid]  = ap * rs;
    }
    // P5b: V biases
    if (tid < 64) {
        ws[OFF_BFEAT + 32 + tid] = bvW[tid] + bva[tid];
        ws[OFF_VPAD + tid] = bva[tid];
    }
}

// ---------------------------------------------------------------------------
// K1: per-pixel features  LV[b][j][hw],  j<32: logits-feat L, j>=32: V-feat
//     acc = x_n @ Wfeat + bfeat   (Wfeat uniform -> scalar loads)
// ---------------------------------------------------------------------------
__global__ __launch_bounds__(256) void k1_feat(
    const float* __restrict__ x, const float* __restrict__ ws,
    float* __restrict__ lv)
{
    const int tid = threadIdx.x;
    const int n  = blockIdx.x * 256 + tid;
    const int b  = n >> 14;
    const int hw = n & 16383;

    const float* Wf = ws + OFF_WFEAT;
    const float* bf = ws + OFF_BFEAT;

    float acc[96];
    #pragma unroll
    for (int j = 0; j < 96; ++j) acc[j] = bf[j];

    const float* xp = x + (size_t)b * 64 * HW + hw;
    for (int c = 0; c < 64; ++c) {
        float xv = xp[(size_t)c * HW];
        const float* w = Wf + c * 96;
        #pragma unroll
        for (int j = 0; j < 96; ++j) acc[j] = fmaf(xv, w[j], acc[j]);
    }

    float* outp = lv + (size_t)b * 96 * HW + hw;
    #pragma unroll
    for (int j = 0; j < 96; ++j) outp[(size_t)j * HW] = acc[j];
}

// ---------------------------------------------------------------------------
// K2: windowed attention + Wo + LayerNorm + pixel-shuffle store
//     tile 8x8 pixels, halo 10x10, thread = (q, pixel)
// ---------------------------------------------------------------------------
__global__ __launch_bounds__(256) void k2_attn(
    const float* __restrict__ lv, const float* __restrict__ ws,
    const float* __restrict__ rel_pos,
    const float* __restrict__ Wo, const float* __restrict__ bo,
    const float* __restrict__ ln_g, const float* __restrict__ ln_b,
    float* __restrict__ out)
{
    __shared__ float Lb[32][104];
    __shared__ float Vb[64][104];
    __shared__ float relS[288];

    const int tid = threadIdx.x;
    const int b  = blockIdx.z;
    const int ty = blockIdx.y, tx = blockIdx.x;

    const float* Lpad = ws + OFF_LPAD;
    const float* vpad = ws + OFF_VPAD;

    // stage halo (10x10 pixels x 96 features)
    for (int i = tid; i < 9600; i += 256) {
        int f = i / 100, p = i % 100;
        int py = p / 10, px = p % 10;
        int gy = ty*8 - 1 + py, gx = tx*8 - 1 + px;
        float val;
        if ((unsigned)gy < 128u && (unsigned)gx < 128u)
            val = lv[((size_t)b*96 + f)*HW + gy*WIDTH + gx];
        else
            val = (f < 32) ? Lpad[f] : vpad[f-32];
        if (f < 32) Lb[f][p] = val; else Vb[f-32][p] = val;
    }
    for (int i = tid; i < 288; i += 256) relS[i] = rel_pos[i];
    __syncthreads();

    const int q   = tid >> 6;       // wave-uniform
    const int pix = tid & 63;
    const int py  = pix >> 3, px = pix & 7;

    float o[64];
    #pragma unroll
    for (int j = 0; j < 64; ++j) o[j] = 0.f;

    #pragma unroll
    for (int h = 0; h < 8; ++h) {
        const int hq = h*4 + q;
        float l[9];
        #pragma unroll
        for (int p = 0; p < 9; ++p) {
            int hp = (py + p/3)*10 + (px + p%3);
            l[p] = Lb[hq][hp] + relS[hq*9 + p];
        }
        float m = l[0];
        #pragma unroll
        for (int p = 1; p < 9; ++p) m = fmaxf(m, l[p]);
        float s = 0.f;
        #pragma unroll
        for (int p = 0; p < 9; ++p) { l[p] = __expf(l[p] - m); s += l[p]; }
        const float rinv = 1.f / s;
        #pragma unroll
        for (int p = 0; p < 9; ++p) {
            float a = l[p] * rinv;
            int hp = (py + p/3)*10 + (px + p%3);
            #pragma unroll
            for (int d = 0; d < 8; ++d)
                o[h*8+d] = fmaf(a, Vb[h*8+d][hp], o[h*8+d]);
        }
    }

    // Wo projection (Wo reads are wave-uniform -> scalar loads)
    float outv[32];
    #pragma unroll
    for (int oc = 0; oc < 32; ++oc) outv[oc] = bo[oc];
    for (int f = 0; f < 64; ++f) {
        float ov = o[f];
        #pragma unroll
        for (int oc = 0; oc < 32; ++oc)
            outv[oc] = fmaf(ov, Wo[f*32 + oc], outv[oc]);
    }

    // LayerNorm over 32
    float mu = 0.f;
    #pragma unroll
    for (int oc = 0; oc < 32; ++oc) mu += outv[oc];
    mu *= (1.f/32.f);
    float var = 0.f;
    #pragma unroll
    for (int oc = 0; oc < 32; ++oc) { float d = outv[oc] - mu; var += d*d; }
    var *= (1.f/32.f);
    const float rstd = rsqrtf(var + 1e-5f);

    // pixel-shuffle store: out[b][oc][2*gy+sy][2*gx+sx], q = sy*2+sx
    const int gy = ty*8 + py, gx = tx*8 + px;
    const int sy = q >> 1, sx = q & 1;
    const int Y = gy*2 + sy, X = gx*2 + sx;
    #pragma unroll
    for (int oc = 0; oc < 32; ++oc) {
        float v = (outv[oc] - mu) * rstd * ln_g[oc] + ln_b[oc];
        out[(((size_t)b*32 + oc)*256 + Y)*256 + X] = v;
    }
}

// ---------------------------------------------------------------------------
extern "C" void kernel_launch(void* const* d_in, const int* in_sizes, int n_in,
                              void* d_out, int out_size, void* d_ws, size_t ws_size,
                              hipStream_t stream)
{
    const float* x        = (const float*)d_in[0];
    const float* up_query = (const float*)d_in[1];
    const float* Wk  = (const float*)d_in[2];
    const float* bk  = (const float*)d_in[3];
    const float* Wv  = (const float*)d_in[4];
    const float* bv  = (const float*)d_in[5];
    const float* Wq  = (const float*)d_in[6];
    const float* bq  = (const float*)d_in[7];
    const float* Wka = (const float*)d_in[8];
    const float* bka = (const float*)d_in[9];
    const float* Wva = (const float*)d_in[10];
    const float* bva = (const float*)d_in[11];
    const float* Wo  = (const float*)d_in[12];
    const float* bo  = (const float*)d_in[13];
    const float* rel_pos = (const float*)d_in[14];
    const float* ln_g = (const float*)d_in[15];
    const float* ln_b = (const float*)d_in[16];

    float* ws  = (float*)d_ws;
    float* out = (float*)d_out;

    const size_t need = (size_t)(OFF_LV + 8*96*HW) * sizeof(float);
    if (ws_size < need) return;  // insufficient scratch -> fail loudly (poison stays)

    k0_fuse<<<1, 256, 0, stream>>>(up_query, Wk, bk, Wv, bv, Wq, bq,
                                   Wka, bka, Wva, bva, ws);
    k1_feat<<<512, 256, 0, stream>>>(x, ws, ws + OFF_LV);
    k2_attn<<<dim3(16,16,8), 256, 0, stream>>>(ws + OFF_LV, ws, rel_pos,
                                               Wo, bo, ln_g, ln_b, out);
}

// Round 2
// 190.926 us; speedup vs baseline: 1.1179x; 1.1179x over previous
//
#include <hip/hip_runtime.h>

// Problem constants
#define HW    16384   // 128*128
#define WIDTH 128

// ws float offsets
#define OFF_WFEAT 0        // [64][96]  fused weight: j<32 -> WL, j>=32 -> WVV
#define OFF_BFEAT 6144     // [96]      fused bias for valid positions
#define OFF_LPAD  6240     // [32]      logit constant for padded window slots
#define OFF_VPAD  6272     // [64]      V constant for padded window slots
#define OFF_LV    6400     // [8][96][16384] per-pixel features (feature-major)

// ---------------------------------------------------------------------------
// K0: fold all weight matrices (tiny, one block)
// ---------------------------------------------------------------------------
__global__ __launch_bounds__(256) void k0_fuse(
    const float* __restrict__ up_query,
    const float* __restrict__ Wk, const float* __restrict__ bk,
    const float* __restrict__ Wv, const float* __restrict__ bv,
    const float* __restrict__ Wq, const float* __restrict__ bq,
    const float* __restrict__ Wka, const float* __restrict__ bka,
    const float* __restrict__ Wva, const float* __restrict__ bva,
    float* __restrict__ ws)
{
    __shared__ float qc[4][64];     // q_const[q][f] = up_query@Wq + bq
    __shared__ float bkW[64];       // bk @ Wka
    __shared__ float bvW[64];       // bv @ Wva
    __shared__ float WKK[64][64];   // Wk @ Wka

    const int tid = threadIdx.x;

    // P1: q_const (256 jobs)
    {
        int q = tid >> 6, f = tid & 63;
        float a = bq[f];
        for (int c = 0; c < 64; ++c) a = fmaf(up_query[q*64+c], Wq[c*64+f], a);
        qc[q][f] = a;
    }
    // P2: bias projections
    if (tid < 64) {
        float a = 0.f, v = 0.f;
        for (int e = 0; e < 64; ++e) {
            a = fmaf(bk[e], Wka[e*64+tid], a);
            v = fmaf(bv[e], Wva[e*64+tid], v);
        }
        bkW[tid] = a; bvW[tid] = v;
    }
    __syncthreads();

    // P3: WKK (to LDS) and WVV (straight to ws)
    for (int i = tid; i < 4096; i += 256) {
        int c = i >> 6, f = i & 63;
        float a = 0.f, v = 0.f;
        for (int e = 0; e < 64; ++e) {
            a = fmaf(Wk[c*64+e], Wka[e*64+f], a);
            v = fmaf(Wv[c*64+e], Wva[e*64+f], v);
        }
        WKK[c][f] = a;
        ws[OFF_WFEAT + c*96 + 32 + f] = v;
    }
    __syncthreads();

    const float rs = 0.35355339059327373f; // 1/sqrt(8)

    // P4: WL[c][hq] = rs * sum_d WKK[c][h*8+d] * qc[q][h*8+d]
    for (int i = tid; i < 2048; i += 256) {
        int c = i >> 5, hq = i & 31;
        int h = hq >> 2, q = hq & 3;
        float a = 0.f;
        for (int d = 0; d < 8; ++d) a = fmaf(WKK[c][h*8+d], qc[q][h*8+d], a);
        ws[OFF_WFEAT + c*96 + hq] = a * rs;
    }
    // P5: logit biases (valid: 2*bk@Wka + bka ; padded: bk@Wka + bka)
    if (tid < 32) {
        int h = tid >> 2, q = tid & 3;
        float av = 0.f, ap = 0.f;
        for (int d = 0; d < 8; ++d) {
            int f = h*8 + d;
            av = fmaf(2.f*bkW[f] + bka[f], qc[q][f], av);
            ap = fmaf(bkW[f] + bka[f], qc[q][f], ap);
        }
        ws[OFF_BFEAT + tid] = av * rs;
        ws[OFF_LPAD + tid]  = ap * rs;
    }
    // P5b: V biases
    if (tid < 64) {
        ws[OFF_BFEAT + 32 + tid] = bvW[tid] + bva[tid];
        ws[OFF_VPAD + tid] = bva[tid];
    }
}

// ---------------------------------------------------------------------------
// K1: per-pixel features  LV[b][j][hw],  j<32: logits-feat L, j>=32: V-feat
// ---------------------------------------------------------------------------
__global__ __launch_bounds__(256) void k1_feat(
    const float* __restrict__ x, const float* __restrict__ ws,
    float* __restrict__ lv)
{
    const int tid = threadIdx.x;
    const int n  = blockIdx.x * 256 + tid;
    const int b  = n >> 14;
    const int hw = n & 16383;

    const float* Wf = ws + OFF_WFEAT;
    const float* bf = ws + OFF_BFEAT;

    float acc[96];
    #pragma unroll
    for (int j = 0; j < 96; ++j) acc[j] = bf[j];

    const float* xp = x + (size_t)b * 64 * HW + hw;
    for (int c = 0; c < 64; ++c) {
        float xv = xp[(size_t)c * HW];
        const float* w = Wf + c * 96;
        #pragma unroll
        for (int j = 0; j < 96; ++j) acc[j] = fmaf(xv, w[j], acc[j]);
    }

    float* outp = lv + (size_t)b * 96 * HW + hw;
    #pragma unroll
    for (int j = 0; j < 96; ++j) outp[(size_t)j * HW] = acc[j];
}

// ---------------------------------------------------------------------------
// K2: windowed attention + Wo + LayerNorm + pixel-shuffle store
//     tile 8x8 pixels, halo 10x10. Lane map: q = tid&3, pix = tid>>2
//     -> per-oc store instruction covers 4 full 64B lines (no RMW).
//     Vb pixel-major + padded stride 68 -> ds_read_b128 PV, ~2-way max.
// ---------------------------------------------------------------------------
__global__ __launch_bounds__(256) void k2_attn(
    const float* __restrict__ lv, const float* __restrict__ ws,
    const float* __restrict__ rel_pos,
    const float* __restrict__ Wo, const float* __restrict__ bo,
    const float* __restrict__ ln_g, const float* __restrict__ ln_b,
    float* __restrict__ out)
{
    __shared__ float Lb[32][104];   // 13312 B  (feature-major, scalar reads)
    __shared__ float Vb[100][68];   // 27200 B  (pixel-major, b128 reads; 272B rows, 16B-aligned)
    __shared__ float relS[288];     // 1152 B

    const int tid = threadIdx.x;

    // XCD-aware swizzle: 2048 blocks, 8 XCDs -> each XCD gets one batch image
    const int flat = blockIdx.x;
    const int wg   = (flat & 7) * 256 + (flat >> 3);
    const int tx = wg & 15;
    const int ty = (wg >> 4) & 15;
    const int b  = wg >> 8;

    const float* Lpad = ws + OFF_LPAD;
    const float* vpad = ws + OFF_VPAD;

    // stage L halo: 32 features x 100 pixels
    for (int i = tid; i < 3200; i += 256) {
        int f = i / 100, p = i - f*100;
        int py = p / 10, px = p - py*10;
        int gy = ty*8 - 1 + py, gx = tx*8 - 1 + px;
        float val = ((unsigned)gy < 128u && (unsigned)gx < 128u)
                  ? lv[((size_t)b*96 + f)*HW + gy*WIDTH + gx] : Lpad[f];
        Lb[f][p] = val;
    }
    // stage V halo: 32 feature-pairs x 100 pixels, float2 -> ds_write_b64
    for (int i = tid; i < 3200; i += 256) {
        int fp = i / 100, p = i - fp*100;
        int f = fp * 2;
        int py = p / 10, px = p - py*10;
        int gy = ty*8 - 1 + py, gx = tx*8 - 1 + px;
        float2 v;
        if ((unsigned)gy < 128u && (unsigned)gx < 128u) {
            const float* base = lv + ((size_t)b*96 + 32 + f)*HW + gy*WIDTH + gx;
            v.x = base[0];
            v.y = base[HW];
        } else {
            v.x = vpad[f]; v.y = vpad[f+1];
        }
        *(float2*)&Vb[p][f] = v;
    }
    for (int i = tid; i < 288; i += 256) relS[i] = rel_pos[i];
    __syncthreads();

    const int q   = tid & 3;        // lane-varying now (store coalescing)
    const int pix = tid >> 2;       // 0..63, 16 pixels per wave
    const int py  = pix >> 3, px = pix & 7;

    float o[64];
    #pragma unroll
    for (int j = 0; j < 64; ++j) o[j] = 0.f;

    #pragma unroll
    for (int h = 0; h < 8; ++h) {
        const int hq = h*4 + q;
        float l[9];
        #pragma unroll
        for (int p = 0; p < 9; ++p) {
            int hp = (py + p/3)*10 + (px + p%3);
            l[p] = Lb[hq][hp] + relS[hq*9 + p];
        }
        float m = l[0];
        #pragma unroll
        for (int p = 1; p < 9; ++p) m = fmaxf(m, l[p]);
        float s = 0.f;
        #pragma unroll
        for (int p = 0; p < 9; ++p) { l[p] = __expf(l[p] - m); s += l[p]; }
        const float rinv = 1.f / s;
        #pragma unroll
        for (int p = 0; p < 9; ++p) {
            float a = l[p] * rinv;
            int hp = (py + p/3)*10 + (px + p%3);
            const float4 v0 = *(const float4*)&Vb[hp][h*8];
            const float4 v1 = *(const float4*)&Vb[hp][h*8 + 4];
            o[h*8+0] = fmaf(a, v0.x, o[h*8+0]);
            o[h*8+1] = fmaf(a, v0.y, o[h*8+1]);
            o[h*8+2] = fmaf(a, v0.z, o[h*8+2]);
            o[h*8+3] = fmaf(a, v0.w, o[h*8+3]);
            o[h*8+4] = fmaf(a, v1.x, o[h*8+4]);
            o[h*8+5] = fmaf(a, v1.y, o[h*8+5]);
            o[h*8+6] = fmaf(a, v1.z, o[h*8+6]);
            o[h*8+7] = fmaf(a, v1.w, o[h*8+7]);
        }
    }

    // Wo projection (wave-uniform weight reads -> scalar loads)
    float outv[32];
    #pragma unroll
    for (int oc = 0; oc < 32; ++oc) outv[oc] = bo[oc];
    for (int f = 0; f < 64; ++f) {
        float ov = o[f];
        #pragma unroll
        for (int oc = 0; oc < 32; ++oc)
            outv[oc] = fmaf(ov, Wo[f*32 + oc], outv[oc]);
    }

    // LayerNorm over 32
    float mu = 0.f;
    #pragma unroll
    for (int oc = 0; oc < 32; ++oc) mu += outv[oc];
    mu *= (1.f/32.f);
    float var = 0.f;
    #pragma unroll
    for (int oc = 0; oc < 32; ++oc) { float d = outv[oc] - mu; var += d*d; }
    var *= (1.f/32.f);
    const float rstd = rsqrtf(var + 1e-5f);

    // pixel-shuffle store: per oc, one wave writes 4 rows x 16 floats = 4 full lines
    const int gy = ty*8 + py, gx = tx*8 + px;
    const int sy = q >> 1, sx = q & 1;
    const int Y = gy*2 + sy, X = gx*2 + sx;
    float* op = out + (((size_t)b*32)*256 + Y)*256 + X;
    #pragma unroll
    for (int oc = 0; oc < 32; ++oc) {
        float v = (outv[oc] - mu) * rstd * ln_g[oc] + ln_b[oc];
        op[(size_t)oc * 65536] = v;
    }
}

// ---------------------------------------------------------------------------
extern "C" void kernel_launch(void* const* d_in, const int* in_sizes, int n_in,
                              void* d_out, int out_size, void* d_ws, size_t ws_size,
                              hipStream_t stream)
{
    const float* x        = (const float*)d_in[0];
    const float* up_query = (const float*)d_in[1];
    const float* Wk  = (const float*)d_in[2];
    const float* bk  = (const float*)d_in[3];
    const float* Wv  = (const float*)d_in[4];
    const float* bv  = (const float*)d_in[5];
    const float* Wq  = (const float*)d_in[6];
    const float* bq  = (const float*)d_in[7];
    const float* Wka = (const float*)d_in[8];
    const float* bka = (const float*)d_in[9];
    const float* Wva = (const float*)d_in[10];
    const float* bva = (const float*)d_in[11];
    const float* Wo  = (const float*)d_in[12];
    const float* bo  = (const float*)d_in[13];
    const float* rel_pos = (const float*)d_in[14];
    const float* ln_g = (const float*)d_in[15];
    const float* ln_b = (const float*)d_in[16];

    float* ws  = (float*)d_ws;
    float* out = (float*)d_out;

    const size_t need = (size_t)(OFF_LV + 8*96*HW) * sizeof(float);
    if (ws_size < need) return;  // insufficient scratch -> fail loudly (poison stays)

    k0_fuse<<<1, 256, 0, stream>>>(up_query, Wk, bk, Wv, bv, Wq, bq,
                                   Wka, bka, Wva, bva, ws);
    k1_feat<<<512, 256, 0, stream>>>(x, ws, ws + OFF_LV);
    k2_attn<<<2048, 256, 0, stream>>>(ws + OFF_LV, ws, rel_pos,
                                      Wo, bo, ln_g, ln_b, out);
}

// Round 3
// 158.360 us; speedup vs baseline: 1.3478x; 1.2056x over previous
//
#include <hip/hip_runtime.h>

// Problem constants
#define HW    16384   // 128*128
#define WIDTH 128

// ws float offsets
#define OFF_WFEAT 0        // [64][96]  fused weight: j<32 -> WL, j>=32 -> WVV
#define OFF_BFEAT 6144     // [96]      fused bias for valid positions
#define OFF_LPAD  6240     // [32]      logit constant for padded window slots
#define OFF_VPAD  6272     // [64]      V constant for padded window slots
#define OFF_LV    6400     // [8][96][16384] per-pixel features (feature-major)

// ---------------------------------------------------------------------------
// K0: fold all weight matrices (tiny, one block)
// ---------------------------------------------------------------------------
__global__ __launch_bounds__(256) void k0_fuse(
    const float* __restrict__ up_query,
    const float* __restrict__ Wk, const float* __restrict__ bk,
    const float* __restrict__ Wv, const float* __restrict__ bv,
    const float* __restrict__ Wq, const float* __restrict__ bq,
    const float* __restrict__ Wka, const float* __restrict__ bka,
    const float* __restrict__ Wva, const float* __restrict__ bva,
    float* __restrict__ ws)
{
    __shared__ float qc[4][64];     // q_const[q][f] = up_query@Wq + bq
    __shared__ float bkW[64];       // bk @ Wka
    __shared__ float bvW[64];       // bv @ Wva
    __shared__ float WKK[64][64];   // Wk @ Wka

    const int tid = threadIdx.x;

    // P1: q_const (256 jobs)
    {
        int q = tid >> 6, f = tid & 63;
        float a = bq[f];
        for (int c = 0; c < 64; ++c) a = fmaf(up_query[q*64+c], Wq[c*64+f], a);
        qc[q][f] = a;
    }
    // P2: bias projections
    if (tid < 64) {
        float a = 0.f, v = 0.f;
        for (int e = 0; e < 64; ++e) {
            a = fmaf(bk[e], Wka[e*64+tid], a);
            v = fmaf(bv[e], Wva[e*64+tid], v);
        }
        bkW[tid] = a; bvW[tid] = v;
    }
    __syncthreads();

    // P3: WKK (to LDS) and WVV (straight to ws)
    for (int i = tid; i < 4096; i += 256) {
        int c = i >> 6, f = i & 63;
        float a = 0.f, v = 0.f;
        for (int e = 0; e < 64; ++e) {
            a = fmaf(Wk[c*64+e], Wka[e*64+f], a);
            v = fmaf(Wv[c*64+e], Wva[e*64+f], v);
        }
        WKK[c][f] = a;
        ws[OFF_WFEAT + c*96 + 32 + f] = v;
    }
    __syncthreads();

    const float rs = 0.35355339059327373f; // 1/sqrt(8)

    // P4: WL[c][hq] = rs * sum_d WKK[c][h*8+d] * qc[q][h*8+d]
    for (int i = tid; i < 2048; i += 256) {
        int c = i >> 5, hq = i & 31;
        int h = hq >> 2, q = hq & 3;
        float a = 0.f;
        for (int d = 0; d < 8; ++d) a = fmaf(WKK[c][h*8+d], qc[q][h*8+d], a);
        ws[OFF_WFEAT + c*96 + hq] = a * rs;
    }
    // P5: logit biases (valid: 2*bk@Wka + bka ; padded: bk@Wka + bka)
    if (tid < 32) {
        int h = tid >> 2, q = tid & 3;
        float av = 0.f, ap = 0.f;
        for (int d = 0; d < 8; ++d) {
            int f = h*8 + d;
            av = fmaf(2.f*bkW[f] + bka[f], qc[q][f], av);
            ap = fmaf(bkW[f] + bka[f], qc[q][f], ap);
        }
        ws[OFF_BFEAT + tid] = av * rs;
        ws[OFF_LPAD + tid]  = ap * rs;
    }
    // P5b: V biases
    if (tid < 64) {
        ws[OFF_BFEAT + 32 + tid] = bvW[tid] + bva[tid];
        ws[OFF_VPAD + tid] = bva[tid];
    }
}

// ---------------------------------------------------------------------------
// K1: per-pixel features  LV[b][j][hw],  j<32: logits-feat L, j>=32: V-feat
//     gridDim.y splits the 96 features into 2 chunks of 48 -> acc[48],
//     no spills, higher occupancy. x is read twice (cheap vs spill traffic).
// ---------------------------------------------------------------------------
__global__ __launch_bounds__(256, 4) void k1_feat(
    const float* __restrict__ x, const float* __restrict__ ws,
    float* __restrict__ lv)
{
    const int tid = threadIdx.x;
    const int n  = blockIdx.x * 256 + tid;
    const int j0 = blockIdx.y * 48;
    const int b  = n >> 14;
    const int hw = n & 16383;

    const float* Wf = ws + OFF_WFEAT + j0;
    const float* bf = ws + OFF_BFEAT + j0;

    float acc[48];
    #pragma unroll
    for (int j = 0; j < 48; ++j) acc[j] = bf[j];

    const float* xp = x + (size_t)b * 64 * HW + hw;
    for (int c = 0; c < 64; ++c) {
        float xv = xp[(size_t)c * HW];
        const float* w = Wf + c * 96;
        #pragma unroll
        for (int j = 0; j < 48; ++j) acc[j] = fmaf(xv, w[j], acc[j]);
    }

    float* outp = lv + ((size_t)b * 96 + j0) * HW + hw;
    #pragma unroll
    for (int j = 0; j < 48; ++j) outp[(size_t)j * HW] = acc[j];
}

// ---------------------------------------------------------------------------
// K2: windowed attention + Wo + LayerNorm + pixel-shuffle store
//     tile 8x8 pixels, halo 10x10. Lane map: q = tid&3, pix = tid>>2.
//     Wo folded in PER HEAD: peak live regs ~55 (outv[32]+oh[8]+l[9]),
//     eliminating the o[64]+outv[32] co-live spill (was ~240 MB HBM writes).
// ---------------------------------------------------------------------------
__global__ __launch_bounds__(256, 3) void k2_attn(
    const float* __restrict__ lv, const float* __restrict__ ws,
    const float* __restrict__ rel_pos,
    const float* __restrict__ Wo, const float* __restrict__ bo,
    const float* __restrict__ ln_g, const float* __restrict__ ln_b,
    float* __restrict__ out)
{
    __shared__ float Lb[32][104];   // 13312 B  (feature-major, scalar reads)
    __shared__ float Vb[100][68];   // 27200 B  (pixel-major, b128 reads)
    __shared__ float relS[288];     // 1152 B

    const int tid = threadIdx.x;

    // XCD-aware swizzle: 2048 blocks, 8 XCDs -> each XCD gets one batch image
    const int flat = blockIdx.x;
    const int wg   = (flat & 7) * 256 + (flat >> 3);
    const int tx = wg & 15;
    const int ty = (wg >> 4) & 15;
    const int b  = wg >> 8;

    const float* Lpad = ws + OFF_LPAD;
    const float* vpad = ws + OFF_VPAD;

    // stage L halo: 32 features x 100 pixels
    for (int i = tid; i < 3200; i += 256) {
        int f = i / 100, p = i - f*100;
        int py = p / 10, px = p - py*10;
        int gy = ty*8 - 1 + py, gx = tx*8 - 1 + px;
        float val = ((unsigned)gy < 128u && (unsigned)gx < 128u)
                  ? lv[((size_t)b*96 + f)*HW + gy*WIDTH + gx] : Lpad[f];
        Lb[f][p] = val;
    }
    // stage V halo: 32 feature-pairs x 100 pixels, float2 -> ds_write_b64
    for (int i = tid; i < 3200; i += 256) {
        int fp = i / 100, p = i - fp*100;
        int f = fp * 2;
        int py = p / 10, px = p - py*10;
        int gy = ty*8 - 1 + py, gx = tx*8 - 1 + px;
        float2 v;
        if ((unsigned)gy < 128u && (unsigned)gx < 128u) {
            const float* base = lv + ((size_t)b*96 + 32 + f)*HW + gy*WIDTH + gx;
            v.x = base[0];
            v.y = base[HW];
        } else {
            v.x = vpad[f]; v.y = vpad[f+1];
        }
        *(float2*)&Vb[p][f] = v;
    }
    for (int i = tid; i < 288; i += 256) relS[i] = rel_pos[i];
    __syncthreads();

    const int q   = tid & 3;        // lane-varying (store coalescing)
    const int pix = tid >> 2;       // 0..63, 16 pixels per wave
    const int py  = pix >> 3, px = pix & 7;

    float outv[32];
    #pragma unroll
    for (int oc = 0; oc < 32; ++oc) outv[oc] = bo[oc];

    #pragma unroll
    for (int h = 0; h < 8; ++h) {
        const int hq = h*4 + q;
        float l[9];
        #pragma unroll
        for (int p = 0; p < 9; ++p) {
            int hp = (py + p/3)*10 + (px + p%3);
            l[p] = Lb[hq][hp] + relS[hq*9 + p];
        }
        float m = l[0];
        #pragma unroll
        for (int p = 1; p < 9; ++p) m = fmaxf(m, l[p]);
        float s = 0.f;
        #pragma unroll
        for (int p = 0; p < 9; ++p) { l[p] = __expf(l[p] - m); s += l[p]; }
        const float rinv = 1.f / s;

        float oh[8];
        #pragma unroll
        for (int d = 0; d < 8; ++d) oh[d] = 0.f;
        #pragma unroll
        for (int p = 0; p < 9; ++p) {
            float a = l[p] * rinv;
            int hp = (py + p/3)*10 + (px + p%3);
            const float4 v0 = *(const float4*)&Vb[hp][h*8];
            const float4 v1 = *(const float4*)&Vb[hp][h*8 + 4];
            oh[0] = fmaf(a, v0.x, oh[0]);
            oh[1] = fmaf(a, v0.y, oh[1]);
            oh[2] = fmaf(a, v0.z, oh[2]);
            oh[3] = fmaf(a, v0.w, oh[3]);
            oh[4] = fmaf(a, v1.x, oh[4]);
            oh[5] = fmaf(a, v1.y, oh[5]);
            oh[6] = fmaf(a, v1.z, oh[6]);
            oh[7] = fmaf(a, v1.w, oh[7]);
        }
        // fold Wo for this head (wave-uniform weight reads -> scalar loads)
        #pragma unroll
        for (int d = 0; d < 8; ++d) {
            float od = oh[d];
            const float* wrow = Wo + (h*8 + d)*32;
            #pragma unroll
            for (int oc = 0; oc < 32; ++oc)
                outv[oc] = fmaf(od, wrow[oc], outv[oc]);
        }
    }

    // LayerNorm over 32
    float mu = 0.f;
    #pragma unroll
    for (int oc = 0; oc < 32; ++oc) mu += outv[oc];
    mu *= (1.f/32.f);
    float var = 0.f;
    #pragma unroll
    for (int oc = 0; oc < 32; ++oc) { float d = outv[oc] - mu; var += d*d; }
    var *= (1.f/32.f);
    const float rstd = rsqrtf(var + 1e-5f);

    // pixel-shuffle store: per oc, one wave writes 4 rows x 16 floats = 4 full lines
    const int gy = ty*8 + py, gx = tx*8 + px;
    const int sy = q >> 1, sx = q & 1;
    const int Y = gy*2 + sy, X = gx*2 + sx;
    float* op = out + (((size_t)b*32)*256 + Y)*256 + X;
    #pragma unroll
    for (int oc = 0; oc < 32; ++oc) {
        float v = (outv[oc] - mu) * rstd * ln_g[oc] + ln_b[oc];
        op[(size_t)oc * 65536] = v;
    }
}

// ---------------------------------------------------------------------------
extern "C" void kernel_launch(void* const* d_in, const int* in_sizes, int n_in,
                              void* d_out, int out_size, void* d_ws, size_t ws_size,
                              hipStream_t stream)
{
    const float* x        = (const float*)d_in[0];
    const float* up_query = (const float*)d_in[1];
    const float* Wk  = (const float*)d_in[2];
    const float* bk  = (const float*)d_in[3];
    const float* Wv  = (const float*)d_in[4];
    const float* bv  = (const float*)d_in[5];
    const float* Wq  = (const float*)d_in[6];
    const float* bq  = (const float*)d_in[7];
    const float* Wka = (const float*)d_in[8];
    const float* bka = (const float*)d_in[9];
    const float* Wva = (const float*)d_in[10];
    const float* bva = (const float*)d_in[11];
    const float* Wo  = (const float*)d_in[12];
    const float* bo  = (const float*)d_in[13];
    const float* rel_pos = (const float*)d_in[14];
    const float* ln_g = (const float*)d_in[15];
    const float* ln_b = (const float*)d_in[16];

    float* ws  = (float*)d_ws;
    float* out = (float*)d_out;

    const size_t need = (size_t)(OFF_LV + 8*96*HW) * sizeof(float);
    if (ws_size < need) return;  // insufficient scratch -> fail loudly (poison stays)

    k0_fuse<<<1, 256, 0, stream>>>(up_query, Wk, bk, Wv, bv, Wq, bq,
                                   Wka, bka, Wva, bva, ws);
    k1_feat<<<dim3(512, 2), 256, 0, stream>>>(x, ws, ws + OFF_LV);
    k2_attn<<<2048, 256, 0, stream>>>(ws + OFF_LV, ws, rel_pos,
                                      Wo, bo, ln_g, ln_b, out);
}

// Round 4
// 138.495 us; speedup vs baseline: 1.5412x; 1.1434x over previous
//
#include <hip/hip_runtime.h>

// Problem constants
#define HW    16384   // 128*128
#define WIDTH 128

// ws layout: [96][104] bf16 fused weight matrix, packed as 4992 dwords.
//   row j (feature), col k: k<64 -> weight[c=k][j]; k=64 -> valid-bias[j];
//   k=65 -> pad-bias[j]; k in [66,104) -> 0.  j<32: logit feats; j>=32: V feats.
#define WFB_DWORDS 4992

typedef short bshort8 __attribute__((ext_vector_type(8)));
typedef float f32x4   __attribute__((ext_vector_type(4)));

static __device__ inline unsigned short f2bf(float f) {
    unsigned u = __builtin_bit_cast(unsigned, f);
    unsigned r = u + 0x7fff + ((u >> 16) & 1);   // RNE
    return (unsigned short)(r >> 16);
}
static __device__ inline float bf2f(unsigned short s) {
    return __builtin_bit_cast(float, (unsigned)s << 16);
}

// ---------------------------------------------------------------------------
// K0: fold all weights into the bf16 [96][104] B-matrix (one block)
// ---------------------------------------------------------------------------
__global__ __launch_bounds__(256) void k0_fuse(
    const float* __restrict__ up_query,
    const float* __restrict__ Wk, const float* __restrict__ bk,
    const float* __restrict__ Wv, const float* __restrict__ bv,
    const float* __restrict__ Wq, const float* __restrict__ bq,
    const float* __restrict__ Wka, const float* __restrict__ bka,
    const float* __restrict__ Wva, const float* __restrict__ bva,
    float* __restrict__ ws)
{
    __shared__ float qc[4][64];
    __shared__ float bkW[64];
    __shared__ float bvW[64];
    __shared__ float WKK[64][64];
    __shared__ float WVVs[64][64];
    __shared__ float bfS[96];    // valid-position bias (logit | V)
    __shared__ float padS[96];   // padded-position constant (logit | V)

    const int tid = threadIdx.x;

    // P1: q_const[q][f] = up_query@Wq + bq
    {
        int q = tid >> 6, f = tid & 63;
        float a = bq[f];
        for (int c = 0; c < 64; ++c) a = fmaf(up_query[q*64+c], Wq[c*64+f], a);
        qc[q][f] = a;
    }
    // P2: bk@Wka, bv@Wva
    if (tid < 64) {
        float a = 0.f, v = 0.f;
        for (int e = 0; e < 64; ++e) {
            a = fmaf(bk[e], Wka[e*64+tid], a);
            v = fmaf(bv[e], Wva[e*64+tid], v);
        }
        bkW[tid] = a; bvW[tid] = v;
    }
    __syncthreads();

    // P3: WKK = Wk@Wka, WVV = Wv@Wva
    for (int i = tid; i < 4096; i += 256) {
        int c = i >> 6, f = i & 63;
        float a = 0.f, v = 0.f;
        for (int e = 0; e < 64; ++e) {
            a = fmaf(Wk[c*64+e], Wka[e*64+f], a);
            v = fmaf(Wv[c*64+e], Wva[e*64+f], v);
        }
        WKK[c][f] = a;
        WVVs[c][f] = v;
    }
    __syncthreads();

    const float rs = 0.35355339059327373f; // 1/sqrt(8)

    // P5: biases. logit part: valid = (2*bkW+bka)@qc*rs ; pad = (bkW+bka)@qc*rs
    if (tid < 32) {
        int h = tid >> 2, q = tid & 3;
        float av = 0.f, ap = 0.f;
        for (int d = 0; d < 8; ++d) {
            int f = h*8 + d;
            av = fmaf(2.f*bkW[f] + bka[f], qc[q][f], av);
            ap = fmaf(bkW[f] + bka[f], qc[q][f], ap);
        }
        bfS[tid] = av * rs;
        padS[tid] = ap * rs;
    } else if (tid < 96) {
        int t = tid - 32;
        bfS[32 + t]  = bvW[t] + bva[t];
        padS[32 + t] = bva[t];
    }
    __syncthreads();

    // P6: emit bf16 B-matrix [96][104] (pairs packed into dwords)
    unsigned* wsd = (unsigned*)ws;
    for (int i = tid; i < WFB_DWORDS; i += 256) {
        int j = i / 52, kd = i - j*52;
        int h = j >> 2, q = j & 3;   // only used when j<32
        float v[2];
        #pragma unroll
        for (int e = 0; e < 2; ++e) {
            int k = kd*2 + e;
            float val;
            if (k < 64) {
                if (j < 32) {
                    float a = 0.f;
                    #pragma unroll
                    for (int d = 0; d < 8; ++d)
                        a = fmaf(WKK[k][h*8+d], qc[q][h*8+d], a);
                    val = a * rs;
                } else {
                    val = WVVs[k][j-32];
                }
            } else if (k == 64) val = bfS[j];
            else if (k == 65)   val = padS[j];
            else                val = 0.f;
            v[e] = val;
        }
        wsd[i] = (unsigned)f2bf(v[0]) | ((unsigned)f2bf(v[1]) << 16);
    }
}

// ---------------------------------------------------------------------------
// K2: fused per-block pipeline.
//  Phase A: stage 10x10 x-halo as bf16 [112][104] (channels 0..63 = x,
//           64/65 = valid/pad flag, 66..95 = 0)  + bf16 rel_pos.
//  Phase B: MFMA 16x16x32_bf16: C[p][j] = xA @ WfB  (42 tiles, acc in regs)
//  Phase C: scatter C -> Lb[32][100] (logit feats), Vb[100][68] (V feats)
//  Phase D: softmax + PV + Wo-fold + LayerNorm + pixel-shuffle store.
// LDS union = 40576 B -> 4 blocks/CU.
// ---------------------------------------------------------------------------
__global__ __launch_bounds__(256, 4) void k2_attn(
    const float* __restrict__ x, const float* __restrict__ wfb,
    const float* __restrict__ rel_pos,
    const float* __restrict__ Wo, const float* __restrict__ bo,
    const float* __restrict__ ln_g, const float* __restrict__ ln_b,
    float* __restrict__ out)
{
    __shared__ __align__(16) char smem[40576];
    // Phase A/B view: bf16 xA[112][104] at bytes [0, 23296)
    // Phase C/D view: float Lb[32][100] at 0, float Vb[100][68] at 12800
    // bytes [40000,40576): bf16 relS[288] (live from phase A onward)

    const int tid = threadIdx.x;

    // XCD-aware swizzle: 2048 blocks, 8 XCDs -> each XCD one batch image
    const int flat = blockIdx.x;
    const int wg   = (flat & 7) * 256 + (flat >> 3);
    const int tx = wg & 15;
    const int ty = (wg >> 4) & 15;
    const int b  = wg >> 8;

    unsigned* xAd = (unsigned*)smem;                        // [112][52] dwords
    unsigned short* relb = (unsigned short*)(smem + 40000); // [288]

    // ---- Phase A: stage x-halo (bf16) + flags + rel ----
    for (int i = tid; i < 5376; i += 256) {
        int kd = i / 112;            // dword col 0..47  (channels 2kd,2kd+1)
        int p  = i - kd*112;         // halo pixel 0..111
        unsigned pack = 0;
        if (p < 100) {
            int py = p / 10, px = p - py*10;
            int gy = ty*8 - 1 + py, gx = tx*8 - 1 + px;
            bool valid = ((unsigned)gy < 128u) && ((unsigned)gx < 128u);
            if (kd < 32) {
                if (valid) {
                    const float* xp = x + (((size_t)b*64 + 2*kd)*HW) + gy*WIDTH + gx;
                    unsigned lo = f2bf(xp[0]);
                    unsigned hi = f2bf(xp[HW]);
                    pack = lo | (hi << 16);
                }
            } else if (kd == 32) {
                // channels 64 (valid flag) / 65 (pad flag), bf16 1.0 = 0x3f80
                pack = valid ? 0x00003f80u : 0x3f800000u;
            }
        }
        xAd[p*52 + kd] = pack;
    }
    for (int i = tid; i < 288; i += 256) relb[i] = f2bf(rel_pos[i]);
    __syncthreads();

    // ---- Phase B: MFMA feature GEMM ----
    const int lane  = tid & 63;
    const int w     = tid >> 6;
    const int frow  = lane & 15;
    const int kchk  = lane >> 4;     // 0..3

    const unsigned short* xAs = (const unsigned short*)smem;
    const unsigned short* wfs = (const unsigned short*)wfb;

    f32x4 accs[11];
    #pragma unroll
    for (int tt = 0; tt < 11; ++tt) {
        int t = w + 4*tt;
        if (t < 42) {
            int mt = t / 6, nt = t - mt*6;
            const unsigned short* arow = xAs + (mt*16 + frow)*104 + kchk*8;
            const unsigned short* brow = wfs + (nt*16 + frow)*104 + kchk*8;
            f32x4 acc = {0.f, 0.f, 0.f, 0.f};
            #pragma unroll
            for (int kk = 0; kk < 3; ++kk) {
                bshort8 a  = *(const bshort8*)(arow + kk*32);
                bshort8 bb = *(const bshort8*)(brow + kk*32);
                acc = __builtin_amdgcn_mfma_f32_16x16x32_bf16(a, bb, acc, 0, 0, 0);
            }
            accs[tt] = acc;
        }
    }
    __syncthreads();   // xA reads done; smem can be repurposed

    // ---- Phase C: scatter C fragments into Lb / Vb ----
    float* Lbf = (float*)smem;             // [32][100]
    float* Vbf = (float*)(smem + 12800);   // [100][68]
    #pragma unroll
    for (int tt = 0; tt < 11; ++tt) {
        int t = w + 4*tt;
        if (t < 42) {
            int mt = t / 6, nt = t - mt*6;
            int f = nt*16 + frow;
            int p0 = mt*16 + kchk*4;
            #pragma unroll
            for (int r = 0; r < 4; ++r) {
                int p = p0 + r;
                if (p < 100) {
                    if (nt < 2) Lbf[f*100 + p]        = accs[tt][r];
                    else        Vbf[p*68 + (f - 32)]  = accs[tt][r];
                }
            }
        }
    }
    __syncthreads();

    // ---- Phase D: attention + Wo + LN + pixel-shuffle store ----
    const int q   = tid & 3;
    const int pix = tid >> 2;
    const int py  = pix >> 3, px = pix & 7;

    float outv[32];
    #pragma unroll
    for (int oc = 0; oc < 32; ++oc) outv[oc] = bo[oc];

    #pragma unroll
    for (int h = 0; h < 8; ++h) {
        const int hq = h*4 + q;
        float l[9];
        #pragma unroll
        for (int p = 0; p < 9; ++p) {
            int hp = (py + p/3)*10 + (px + p%3);
            l[p] = Lbf[hq*100 + hp] + bf2f(relb[hq*9 + p]);
        }
        float m = l[0];
        #pragma unroll
        for (int p = 1; p < 9; ++p) m = fmaxf(m, l[p]);
        float s = 0.f;
        #pragma unroll
        for (int p = 0; p < 9; ++p) { l[p] = __expf(l[p] - m); s += l[p]; }
        const float rinv = 1.f / s;

        float oh[8];
        #pragma unroll
        for (int d = 0; d < 8; ++d) oh[d] = 0.f;
        #pragma unroll
        for (int p = 0; p < 9; ++p) {
            float a = l[p] * rinv;
            int hp = (py + p/3)*10 + (px + p%3);
            const float4 v0 = *(const float4*)&Vbf[hp*68 + h*8];
            const float4 v1 = *(const float4*)&Vbf[hp*68 + h*8 + 4];
            oh[0] = fmaf(a, v0.x, oh[0]);
            oh[1] = fmaf(a, v0.y, oh[1]);
            oh[2] = fmaf(a, v0.z, oh[2]);
            oh[3] = fmaf(a, v0.w, oh[3]);
            oh[4] = fmaf(a, v1.x, oh[4]);
            oh[5] = fmaf(a, v1.y, oh[5]);
            oh[6] = fmaf(a, v1.z, oh[6]);
            oh[7] = fmaf(a, v1.w, oh[7]);
        }
        // fold Wo for this head (wave-uniform -> scalar loads)
        #pragma unroll
        for (int d = 0; d < 8; ++d) {
            float od = oh[d];
            const float* wrow = Wo + (h*8 + d)*32;
            #pragma unroll
            for (int oc = 0; oc < 32; ++oc)
                outv[oc] = fmaf(od, wrow[oc], outv[oc]);
        }
    }

    // LayerNorm over 32
    float mu = 0.f;
    #pragma unroll
    for (int oc = 0; oc < 32; ++oc) mu += outv[oc];
    mu *= (1.f/32.f);
    float var = 0.f;
    #pragma unroll
    for (int oc = 0; oc < 32; ++oc) { float d = outv[oc] - mu; var += d*d; }
    var *= (1.f/32.f);
    const float rstd = rsqrtf(var + 1e-5f);

    // pixel-shuffle store: per oc, one wave writes 4 rows x 16 floats
    const int gy = ty*8 + py, gx = tx*8 + px;
    const int sy = q >> 1, sx = q & 1;
    const int Y = gy*2 + sy, X = gx*2 + sx;
    float* op = out + (((size_t)b*32)*256 + Y)*256 + X;
    #pragma unroll
    for (int oc = 0; oc < 32; ++oc) {
        float v = (outv[oc] - mu) * rstd * ln_g[oc] + ln_b[oc];
        op[(size_t)oc * 65536] = v;
    }
}

// ---------------------------------------------------------------------------
extern "C" void kernel_launch(void* const* d_in, const int* in_sizes, int n_in,
                              void* d_out, int out_size, void* d_ws, size_t ws_size,
                              hipStream_t stream)
{
    const float* x        = (const float*)d_in[0];
    const float* up_query = (const float*)d_in[1];
    const float* Wk  = (const float*)d_in[2];
    const float* bk  = (const float*)d_in[3];
    const float* Wv  = (const float*)d_in[4];
    const float* bv  = (const float*)d_in[5];
    const float* Wq  = (const float*)d_in[6];
    const float* bq  = (const float*)d_in[7];
    const float* Wka = (const float*)d_in[8];
    const float* bka = (const float*)d_in[9];
    const float* Wva = (const float*)d_in[10];
    const float* bva = (const float*)d_in[11];
    const float* Wo  = (const float*)d_in[12];
    const float* bo  = (const float*)d_in[13];
    const float* rel_pos = (const float*)d_in[14];
    const float* ln_g = (const float*)d_in[15];
    const float* ln_b = (const float*)d_in[16];

    float* ws  = (float*)d_ws;
    float* out = (float*)d_out;

    if (ws_size < (size_t)WFB_DWORDS * 4) return;

    k0_fuse<<<1, 256, 0, stream>>>(up_query, Wk, bk, Wv, bv, Wq, bq,
                                   Wka, bka, Wva, bva, ws);
    k2_attn<<<2048, 256, 0, stream>>>(x, ws, rel_pos,
                                      Wo, bo, ln_g, ln_b, out);
}

// Round 5
// 107.209 us; speedup vs baseline: 1.9909x; 1.2918x over previous
//
#include <hip/hip_runtime.h>

// Problem constants
#define HW    16384   // 128*128
#define WIDTH 128
#define LOG2E 1.4426950408889634f

// ws layout (dwords):
//  [0, 4992):        wfb  — bf16 [96][104] fused feature B-matrix (logit rows prescaled by LOG2E)
//  [4992, 6016):     wot  — bf16 [32][64]  Wo^T (col-major Wo) for the epilogue MFMA
#define WFB_DWORDS 4992
#define WOT_DWORDS 1024

typedef short bshort8 __attribute__((ext_vector_type(8)));
typedef float f32x4   __attribute__((ext_vector_type(4)));
typedef unsigned u32x4 __attribute__((ext_vector_type(4)));

static __device__ inline unsigned short f2bf(float f) {
    unsigned u = __builtin_bit_cast(unsigned, f);
    unsigned r = u + 0x7fff + ((u >> 16) & 1);   // RNE
    return (unsigned short)(r >> 16);
}
static __device__ inline float bf2f(unsigned short s) {
    return __builtin_bit_cast(float, (unsigned)s << 16);
}
static __device__ inline unsigned cvtpk(float lo, float hi) {
    unsigned d;
    asm("v_cvt_pk_bf16_f32 %0, %1, %2" : "=v"(d) : "v"(lo), "v"(hi));
    return d;
}

// ---------------------------------------------------------------------------
// K0: fold all weights (one block)
// ---------------------------------------------------------------------------
__global__ __launch_bounds__(256) void k0_fuse(
    const float* __restrict__ up_query,
    const float* __restrict__ Wk, const float* __restrict__ bk,
    const float* __restrict__ Wv, const float* __restrict__ bv,
    const float* __restrict__ Wq, const float* __restrict__ bq,
    const float* __restrict__ Wka, const float* __restrict__ bka,
    const float* __restrict__ Wva, const float* __restrict__ bva,
    const float* __restrict__ Wo,
    float* __restrict__ ws)
{
    __shared__ float qc[4][64];
    __shared__ float bkW[64];
    __shared__ float bvW[64];
    __shared__ float WKK[64][64];
    __shared__ float WVVs[64][64];
    __shared__ float bfS[96];    // valid-position bias (logit | V)
    __shared__ float padS[96];   // padded-position constant (logit | V)

    const int tid = threadIdx.x;

    // P1: q_const[q][f] = up_query@Wq + bq
    {
        int q = tid >> 6, f = tid & 63;
        float a = bq[f];
        for (int c = 0; c < 64; ++c) a = fmaf(up_query[q*64+c], Wq[c*64+f], a);
        qc[q][f] = a;
    }
    // P2: bk@Wka, bv@Wva
    if (tid < 64) {
        float a = 0.f, v = 0.f;
        for (int e = 0; e < 64; ++e) {
            a = fmaf(bk[e], Wka[e*64+tid], a);
            v = fmaf(bv[e], Wva[e*64+tid], v);
        }
        bkW[tid] = a; bvW[tid] = v;
    }
    __syncthreads();

    // P3: WKK = Wk@Wka, WVV = Wv@Wva
    for (int i = tid; i < 4096; i += 256) {
        int c = i >> 6, f = i & 63;
        float a = 0.f, v = 0.f;
        for (int e = 0; e < 64; ++e) {
            a = fmaf(Wk[c*64+e], Wka[e*64+f], a);
            v = fmaf(Wv[c*64+e], Wva[e*64+f], v);
        }
        WKK[c][f] = a;
        WVVs[c][f] = v;
    }
    __syncthreads();

    const float rs = 0.35355339059327373f; // 1/sqrt(8)

    // P5: biases. logit: valid = (2*bkW+bka)@qc*rs ; pad = (bkW+bka)@qc*rs
    if (tid < 32) {
        int h = tid >> 2, q = tid & 3;
        float av = 0.f, ap = 0.f;
        for (int d = 0; d < 8; ++d) {
            int f = h*8 + d;
            av = fmaf(2.f*bkW[f] + bka[f], qc[q][f], av);
            ap = fmaf(bkW[f] + bka[f], qc[q][f], ap);
        }
        bfS[tid] = av * rs;
        padS[tid] = ap * rs;
    } else if (tid < 96) {
        int t = tid - 32;
        bfS[32 + t]  = bvW[t] + bva[t];
        padS[32 + t] = bva[t];
    }
    __syncthreads();

    // P6: emit bf16 B-matrix [96][104]; logit rows (j<32) prescaled by LOG2E
    unsigned* wsd = (unsigned*)ws;
    for (int i = tid; i < WFB_DWORDS; i += 256) {
        int j = i / 52, kd = i - j*52;
        int h = j >> 2, q = j & 3;   // used when j<32
        float v[2];
        #pragma unroll
        for (int e = 0; e < 2; ++e) {
            int k = kd*2 + e;
            float val;
            if (k < 64) {
                if (j < 32) {
                    float a = 0.f;
                    #pragma unroll
                    for (int d = 0; d < 8; ++d)
                        a = fmaf(WKK[k][h*8+d], qc[q][h*8+d], a);
                    val = a * rs;
                } else {
                    val = WVVs[k][j-32];
                }
            } else if (k == 64) val = bfS[j];
            else if (k == 65)   val = padS[j];
            else                val = 0.f;
            if (j < 32) val *= LOG2E;
            v[e] = val;
        }
        wsd[i] = (unsigned)f2bf(v[0]) | ((unsigned)f2bf(v[1]) << 16);
    }
    // P7: WoT bf16 [32 col][64 k]
    for (int i = tid; i < WOT_DWORDS; i += 256) {
        int col = i >> 5, kp = i & 31;
        float lo = Wo[(2*kp)*32 + col];
        float hi = Wo[(2*kp+1)*32 + col];
        wsd[WFB_DWORDS + i] = (unsigned)f2bf(lo) | ((unsigned)f2bf(hi) << 16);
    }
}

// ---------------------------------------------------------------------------
// K2: fused pipeline.
//  A: stage 10x10 x-halo bf16 into xA[112 rows][256B] (XOR-swizzled), + rel.
//  B: MFMA feature GEMM  C[p][j] = xA @ wfb  (42 tiles, accs in regs)
//  C: scatter -> Lbf[32][100] f32, Vbf[100][68] f32
//  D: wave = head-pair, lane = pixel, all 4 q per thread:
//     softmax (exp2-domain) + PV (V reads shared across q) -> bf16 O rows
//  E: O[256][64]bf16 in swizzled LDS -> MFMA x WoT -> C[256][32] -> LN -> store
// LDS 40960 B -> 4 blocks/CU.
// ---------------------------------------------------------------------------
__global__ __launch_bounds__(256, 4) void k2_attn(
    const float* __restrict__ x, const float* __restrict__ ws,
    const float* __restrict__ rel_pos,
    const float* __restrict__ bo,
    const float* __restrict__ ln_g, const float* __restrict__ ln_b,
    float* __restrict__ out)
{
    __shared__ __align__(16) char smem[40960];
    // A/B view : bf16 xA rows p=0..111, 256B stride, off ^= (p&7)<<4   [0,28672)
    // C/D view : float Lbf[32][100] @0 ; float Vbf[100][68] @12800     [0,40000)
    // E view   : bf16 O[256][128B swz] then f32 C[256][128B swz]       [0,32768)
    // relb bf16[288] @40000 (staged in A, dead after D)

    const int tid = threadIdx.x;

    // XCD-aware swizzle: 2048 blocks, 8 XCDs -> each XCD one batch image
    const int flat = blockIdx.x;
    const int wg   = (flat & 7) * 256 + (flat >> 3);
    const int tx = wg & 15;
    const int ty = (wg >> 4) & 15;
    const int b  = wg >> 8;

    unsigned short* relb = (unsigned short*)(smem + 40000);

    // ---- Phase A ----
    for (int i = tid; i < 1344; i += 256) {
        int kq = i / 112, p = i - kq*112;     // kq: 16B chunk (8 channels)
        u32x4 pack = {0u, 0u, 0u, 0u};
        if (p < 100) {
            int py = p / 10, px = p - py*10;
            int gy = ty*8 - 1 + py, gx = tx*8 - 1 + px;
            bool valid = ((unsigned)gy < 128u) && ((unsigned)gx < 128u);
            if (kq < 8) {
                if (valid) {
                    const float* xp = x + ((size_t)b*64 + kq*8)*HW + gy*WIDTH + gx;
                    #pragma unroll
                    for (int e = 0; e < 4; ++e)
                        pack[e] = cvtpk(xp[(size_t)(2*e)*HW], xp[(size_t)(2*e+1)*HW]);
                }
            } else if (kq == 8) {
                // bf16 flags: ch64=valid(1.0), ch65=pad(1.0)
                pack[0] = valid ? 0x00003f80u : 0x3f800000u;
            }
        }
        *(u32x4*)(smem + p*256 + (((unsigned)(kq*16)) ^ (((unsigned)(p & 7)) << 4))) = pack;
    }
    for (int i = tid; i < 288; i += 256) relb[i] = f2bf(rel_pos[i] * LOG2E);
    __syncthreads();

    const int lane = tid & 63;
    const int wv   = tid >> 6;
    const int frow = lane & 15;
    const int kseg = lane >> 4;

    // ---- Phase B: feature GEMM ----
    const unsigned short* wfs = (const unsigned short*)ws;
    f32x4 accs[11];
    #pragma unroll
    for (int tt = 0; tt < 11; ++tt) {
        int t = wv + 4*tt;
        if (t < 42) {
            int mt = t / 6, nt = t - mt*6;
            int arow = mt*16 + frow;
            const unsigned asw = ((unsigned)(arow & 7)) << 4;
            const unsigned short* brow = wfs + (nt*16 + frow)*104 + kseg*8;
            f32x4 acc = {0.f, 0.f, 0.f, 0.f};
            #pragma unroll
            for (int kk = 0; kk < 3; ++kk) {
                bshort8 a  = *(const bshort8*)(smem + arow*256
                                 + (((unsigned)(kseg*16 + kk*64)) ^ asw));
                bshort8 bb = *(const bshort8*)(brow + kk*32);
                acc = __builtin_amdgcn_mfma_f32_16x16x32_bf16(a, bb, acc, 0, 0, 0);
            }
            accs[tt] = acc;
        }
    }
    __syncthreads();   // xA dead

    // ---- Phase C: scatter into Lbf / Vbf ----
    float* Lbf = (float*)smem;             // [32][100]
    float* Vbf = (float*)(smem + 12800);   // [100][68]
    #pragma unroll
    for (int tt = 0; tt < 11; ++tt) {
        int t = wv + 4*tt;
        if (t < 42) {
            int mt = t / 6, nt = t - mt*6;
            int f = nt*16 + frow;
            int p0 = mt*16 + kseg*4;
            #pragma unroll
            for (int r = 0; r < 4; ++r) {
                int p = p0 + r;
                if (p < 100) {
                    if (nt < 2) Lbf[f*100 + p]       = accs[tt][r];
                    else        Vbf[p*68 + (f - 32)] = accs[tt][r];
                }
            }
        }
    }
    __syncthreads();

    // ---- Phase D: wave = head-pair, lane = pixel, all 4 q ----
    const int dpy = lane >> 3, dpx = lane & 7;
    const int pbase = dpy*10 + dpx;

    unsigned od[32];   // packed bf16 O: [(q*2+hh)*4 + t]
    #pragma unroll
    for (int hh = 0; hh < 2; ++hh) {
        const int h = wv*2 + hh;
        float a[4][9];
        #pragma unroll
        for (int q = 0; q < 4; ++q) {
            const int hq = h*4 + q;
            const float* Lrow = Lbf + hq*100 + pbase;
            const unsigned short* rrow = relb + hq*9;
            float l[9];
            #pragma unroll
            for (int n = 0; n < 9; ++n)
                l[n] = Lrow[(n/3)*10 + (n%3)] + bf2f(rrow[n]);
            float m = l[0];
            #pragma unroll
            for (int n = 1; n < 9; ++n) m = fmaxf(m, l[n]);
            float s = 0.f;
            #pragma unroll
            for (int n = 0; n < 9; ++n) { l[n] = exp2f(l[n] - m); s += l[n]; }
            const float rinv = __builtin_amdgcn_rcpf(s);
            #pragma unroll
            for (int n = 0; n < 9; ++n) a[q][n] = l[n] * rinv;
        }
        float o8[4][8];
        #pragma unroll
        for (int q = 0; q < 4; ++q)
            #pragma unroll
            for (int d = 0; d < 8; ++d) o8[q][d] = 0.f;
        #pragma unroll
        for (int n = 0; n < 9; ++n) {
            const float* vp = Vbf + (pbase + (n/3)*10 + (n%3))*68 + h*8;
            const f32x4 v0 = *(const f32x4*)vp;
            const f32x4 v1 = *(const f32x4*)(vp + 4);
            #pragma unroll
            for (int q = 0; q < 4; ++q) {
                const float aq = a[q][n];
                o8[q][0] = fmaf(aq, v0[0], o8[q][0]);
                o8[q][1] = fmaf(aq, v0[1], o8[q][1]);
                o8[q][2] = fmaf(aq, v0[2], o8[q][2]);
                o8[q][3] = fmaf(aq, v0[3], o8[q][3]);
                o8[q][4] = fmaf(aq, v1[0], o8[q][4]);
                o8[q][5] = fmaf(aq, v1[1], o8[q][5]);
                o8[q][6] = fmaf(aq, v1[2], o8[q][6]);
                o8[q][7] = fmaf(aq, v1[3], o8[q][7]);
            }
        }
        #pragma unroll
        for (int q = 0; q < 4; ++q)
            #pragma unroll
            for (int t = 0; t < 4; ++t)
                od[(q*2 + hh)*4 + t] = cvtpk(o8[q][2*t], o8[q][2*t + 1]);
    }
    __syncthreads();   // Lbf/Vbf dead

    // O-writes: row = lane*4+q (128B rows, off ^= ((row>>2)&7)<<4 = (lane&7)<<4)
    {
        const unsigned sw = ((unsigned)(lane & 7)) << 4;
        #pragma unroll
        for (int q = 0; q < 4; ++q) {
            const int row = lane*4 + q;
            #pragma unroll
            for (int hh = 0; hh < 2; ++hh) {
                u32x4 w4 = { od[(q*2+hh)*4+0], od[(q*2+hh)*4+1],
                             od[(q*2+hh)*4+2], od[(q*2+hh)*4+3] };
                *(u32x4*)(smem + row*128 + (((unsigned)(wv*32 + hh*16)) ^ sw)) = w4;
            }
        }
    }
    __syncthreads();   // O complete (cross-wave)

    // ---- Phase E: Wo via MFMA; wave wv owns rows [wv*64, wv*64+64) ----
    const unsigned short* wot = wfs + WFB_DWORDS*2;
    bshort8 av[4][2];
    #pragma unroll
    for (int mt = 0; mt < 4; ++mt) {
        const int row = wv*64 + mt*16 + frow;
        const unsigned sw = (((unsigned)(row >> 2)) & 7u) << 4;
        #pragma unroll
        for (int ks = 0; ks < 2; ++ks)
            av[mt][ks] = *(const bshort8*)(smem + row*128
                             + (((unsigned)(kseg*16 + ks*64)) ^ sw));
    }
    bshort8 bv_[2][2];
    #pragma unroll
    for (int nt = 0; nt < 2; ++nt) {
        const int col = nt*16 + frow;
        #pragma unroll
        for (int ks = 0; ks < 2; ++ks)
            bv_[nt][ks] = *(const bshort8*)(wot + col*64 + kseg*8 + ks*32);
    }
    f32x4 cacc[4][2];
    #pragma unroll
    for (int mt = 0; mt < 4; ++mt)
        #pragma unroll
        for (int nt = 0; nt < 2; ++nt)
            cacc[mt][nt] = (f32x4){0.f, 0.f, 0.f, 0.f};
    #pragma unroll
    for (int ks = 0; ks < 2; ++ks)
        #pragma unroll
        for (int mt = 0; mt < 4; ++mt)
            #pragma unroll
            for (int nt = 0; nt < 2; ++nt)
                cacc[mt][nt] = __builtin_amdgcn_mfma_f32_16x16x32_bf16(
                    av[mt][ks], bv_[nt][ks], cacc[mt][nt], 0, 0, 0);

    // C-write into own 8KB slice (overwrites own O region; only own wave reads)
    #pragma unroll
    for (int mt = 0; mt < 4; ++mt)
        #pragma unroll
        for (int nt = 0; nt < 2; ++nt)
            #pragma unroll
            for (int r = 0; r < 4; ++r) {
                const int row = wv*64 + mt*16 + kseg*4 + r;
                const int col = nt*16 + frow;
                *(float*)(smem + row*128
                    + (((unsigned)(col*4)) ^ ((((unsigned)(row >> 2)) & 7u) << 4)))
                    = cacc[mt][nt][r];
            }
    asm volatile("s_waitcnt lgkmcnt(0)" ::: "memory");

    // C-read own row (= tid), add bo, LN, pixel-shuffle store
    float cv[32];
    {
        const unsigned sw = (((unsigned)(tid >> 2)) & 7u) << 4;
        #pragma unroll
        for (int j = 0; j < 8; ++j) {
            const f32x4 c4 = *(const f32x4*)(smem + tid*128 + (((unsigned)(j*16)) ^ sw));
            cv[j*4+0] = c4[0]; cv[j*4+1] = c4[1]; cv[j*4+2] = c4[2]; cv[j*4+3] = c4[3];
        }
    }
    float mu = 0.f;
    #pragma unroll
    for (int oc = 0; oc < 32; ++oc) { cv[oc] += bo[oc]; mu += cv[oc]; }
    mu *= (1.f/32.f);
    float var = 0.f;
    #pragma unroll
    for (int oc = 0; oc < 32; ++oc) { float d = cv[oc] - mu; var += d*d; }
    var *= (1.f/32.f);
    const float rstd = rsqrtf(var + 1e-5f);

    const int q   = tid & 3;
    const int pix = tid >> 2;
    const int gy = ty*8 + (pix >> 3), gx = tx*8 + (pix & 7);
    const int Y = gy*2 + (q >> 1), X = gx*2 + (q & 1);
    float* op = out + (((size_t)b*32)*256 + Y)*256 + X;
    #pragma unroll
    for (int oc = 0; oc < 32; ++oc) {
        float v = (cv[oc] - mu) * rstd * ln_g[oc] + ln_b[oc];
        op[(size_t)oc * 65536] = v;
    }
}

// ---------------------------------------------------------------------------
extern "C" void kernel_launch(void* const* d_in, const int* in_sizes, int n_in,
                              void* d_out, int out_size, void* d_ws, size_t ws_size,
                              hipStream_t stream)
{
    const float* x        = (const float*)d_in[0];
    const float* up_query = (const float*)d_in[1];
    const float* Wk  = (const float*)d_in[2];
    const float* bk  = (const float*)d_in[3];
    const float* Wv  = (const float*)d_in[4];
    const float* bv  = (const float*)d_in[5];
    const float* Wq  = (const float*)d_in[6];
    const float* bq  = (const float*)d_in[7];
    const float* Wka = (const float*)d_in[8];
    const float* bka = (const float*)d_in[9];
    const float* Wva = (const float*)d_in[10];
    const float* bva = (const float*)d_in[11];
    const float* Wo  = (const float*)d_in[12];
    const float* bo  = (const float*)d_in[13];
    const float* rel_pos = (const float*)d_in[14];
    const float* ln_g = (const float*)d_in[15];
    const float* ln_b = (const float*)d_in[16];

    float* ws  = (float*)d_ws;
    float* out = (float*)d_out;

    if (ws_size < (size_t)(WFB_DWORDS + WOT_DWORDS) * 4) return;

    k0_fuse<<<1, 256, 0, stream>>>(up_query, Wk, bk, Wv, bv, Wq, bq,
                                   Wka, bka, Wva, bva, Wo, ws);
    k2_attn<<<2048, 256, 0, stream>>>(x, ws, rel_pos,
                                      bo, ln_g, ln_b, out);
}

// Round 6
// 103.119 us; speedup vs baseline: 2.0699x; 1.0397x over previous
//
#include <hip/hip_runtime.h>

// Problem constants
#define HW    16384   // 128*128
#define WIDTH 128
#define LOG2E 1.4426950408889634f

// ws layout (dwords):
//  [0, 4992):     wfb — bf16 [96][104] fused feature B-matrix (logit rows pre-scaled by LOG2E)
//  [4992, 6016):  wot — bf16 [32][64] Wo^T for the epilogue MFMA
//  [6016, 6304):  rel — f32 [32][9], pre-scaled by LOG2E
#define WFB_DWORDS 4992
#define WOT_DWORDS 1024
#define REL_OFF    (WFB_DWORDS + WOT_DWORDS)

typedef short bshort8 __attribute__((ext_vector_type(8)));
typedef float f32x4   __attribute__((ext_vector_type(4)));
typedef float f32x2   __attribute__((ext_vector_type(2)));
typedef unsigned u32x4 __attribute__((ext_vector_type(4)));

static __device__ inline unsigned short f2bf(float f) {
    unsigned u = __builtin_bit_cast(unsigned, f);
    unsigned r = u + 0x7fff + ((u >> 16) & 1);   // RNE
    return (unsigned short)(r >> 16);
}
static __device__ inline unsigned cvtpk(float lo, float hi) {
    unsigned d;
    asm("v_cvt_pk_bf16_f32 %0, %1, %2" : "=v"(d) : "v"(lo), "v"(hi));
    return d;
}
static __device__ inline f32x2 pkfma(f32x2 o, f32x2 a, f32x2 v) {
    asm("v_pk_fma_f32 %0, %1, %2, %0" : "+v"(o) : "v"(a), "v"(v));
    return o;
}
static __device__ inline f32x2 pkmul(f32x2 a, f32x2 b) {
    f32x2 d;
    asm("v_pk_mul_f32 %0, %1, %2" : "=v"(d) : "v"(a), "v"(b));
    return d;
}

// ---------------------------------------------------------------------------
// K0: fold all weights (one block)
// ---------------------------------------------------------------------------
__global__ __launch_bounds__(256) void k0_fuse(
    const float* __restrict__ up_query,
    const float* __restrict__ Wk, const float* __restrict__ bk,
    const float* __restrict__ Wv, const float* __restrict__ bv,
    const float* __restrict__ Wq, const float* __restrict__ bq,
    const float* __restrict__ Wka, const float* __restrict__ bka,
    const float* __restrict__ Wva, const float* __restrict__ bva,
    const float* __restrict__ Wo, const float* __restrict__ rel_pos,
    float* __restrict__ ws)
{
    __shared__ float qc[4][64];
    __shared__ float bkW[64];
    __shared__ float bvW[64];
    __shared__ float WKK[64][64];
    __shared__ float WVVs[64][64];
    __shared__ float bfS[96];    // valid-position bias (logit | V)
    __shared__ float padS[96];   // padded-position constant (logit | V)

    const int tid = threadIdx.x;

    // P1: q_const[q][f] = up_query@Wq + bq
    {
        int q = tid >> 6, f = tid & 63;
        float a = bq[f];
        for (int c = 0; c < 64; ++c) a = fmaf(up_query[q*64+c], Wq[c*64+f], a);
        qc[q][f] = a;
    }
    // P2: bk@Wka, bv@Wva
    if (tid < 64) {
        float a = 0.f, v = 0.f;
        for (int e = 0; e < 64; ++e) {
            a = fmaf(bk[e], Wka[e*64+tid], a);
            v = fmaf(bv[e], Wva[e*64+tid], v);
        }
        bkW[tid] = a; bvW[tid] = v;
    }
    __syncthreads();

    // P3: WKK = Wk@Wka, WVV = Wv@Wva
    for (int i = tid; i < 4096; i += 256) {
        int c = i >> 6, f = i & 63;
        float a = 0.f, v = 0.f;
        for (int e = 0; e < 64; ++e) {
            a = fmaf(Wk[c*64+e], Wka[e*64+f], a);
            v = fmaf(Wv[c*64+e], Wva[e*64+f], v);
        }
        WKK[c][f] = a;
        WVVs[c][f] = v;
    }
    __syncthreads();

    const float rs = 0.35355339059327373f; // 1/sqrt(8)

    // P5: biases. logit: valid = (2*bkW+bka)@qc*rs ; pad = (bkW+bka)@qc*rs
    if (tid < 32) {
        int h = tid >> 2, q = tid & 3;
        float av = 0.f, ap = 0.f;
        for (int d = 0; d < 8; ++d) {
            int f = h*8 + d;
            av = fmaf(2.f*bkW[f] + bka[f], qc[q][f], av);
            ap = fmaf(bkW[f] + bka[f], qc[q][f], ap);
        }
        bfS[tid] = av * rs;
        padS[tid] = ap * rs;
    } else if (tid < 96) {
        int t = tid - 32;
        bfS[32 + t]  = bvW[t] + bva[t];
        padS[32 + t] = bva[t];
    }
    __syncthreads();

    // P6: emit bf16 B-matrix [96][104]; logit rows (j<32) pre-scaled by LOG2E
    unsigned* wsd = (unsigned*)ws;
    for (int i = tid; i < WFB_DWORDS; i += 256) {
        int j = i / 52, kd = i - j*52;
        int h = j >> 2, q = j & 3;   // used when j<32
        float v[2];
        #pragma unroll
        for (int e = 0; e < 2; ++e) {
            int k = kd*2 + e;
            float val;
            if (k < 64) {
                if (j < 32) {
                    float a = 0.f;
                    #pragma unroll
                    for (int d = 0; d < 8; ++d)
                        a = fmaf(WKK[k][h*8+d], qc[q][h*8+d], a);
                    val = a * rs;
                } else {
                    val = WVVs[k][j-32];
                }
            } else if (k == 64) val = bfS[j];
            else if (k == 65)   val = padS[j];
            else                val = 0.f;
            if (j < 32) val *= LOG2E;
            v[e] = val;
        }
        wsd[i] = (unsigned)f2bf(v[0]) | ((unsigned)f2bf(v[1]) << 16);
    }
    // P7: WoT bf16 [32 col][64 k]
    for (int i = tid; i < WOT_DWORDS; i += 256) {
        int col = i >> 5, kp = i & 31;
        float lo = Wo[(2*kp)*32 + col];
        float hi = Wo[(2*kp+1)*32 + col];
        wsd[WFB_DWORDS + i] = (unsigned)f2bf(lo) | ((unsigned)f2bf(hi) << 16);
    }
    // P8: rel (f32, exp2-domain)
    for (int i = tid; i < 288; i += 256)
        ws[REL_OFF + i] = rel_pos[i] * LOG2E;
}

// ---------------------------------------------------------------------------
// K2: fused pipeline.
//  A: stage 10x10 x-halo bf16 into xA[112 rows][256B] (XOR-swizzled)
//  B: MFMA feature GEMM, A-operand = wfb, B-operand = xA:
//     lane holds 4 consecutive FEATURES of one PIXEL.
//  C: scatter -> Lbf[100][33] f32 (pixel-major, odd stride), Vbf[100][68] f32 (b128)
//  D: wave = head-pair, lane = pixel: no-max exp2 softmax (deferred 1/sum),
//     PV via v_pk_fma_f32, V reads shared across the 4 q's -> bf16 O rows
//  E: O[256][128B swz] bf16 -> MFMA x WoT -> C f32 (in place) -> LN -> store
// LDS 40448 B -> 4 blocks/CU.
// ---------------------------------------------------------------------------
__global__ __launch_bounds__(256, 4) void k2_attn(
    const float* __restrict__ x, const float* __restrict__ ws,
    const float* __restrict__ bo,
    const float* __restrict__ ln_g, const float* __restrict__ ln_b,
    float* __restrict__ out)
{
    __shared__ __align__(16) char smem[40448];
    // A/B view : bf16 xA rows p=0..111, 256B stride, off ^= (p&7)<<4   [0,28672)
    // C/D view : float Lbf[100][33] @0 ; float Vbf[100][68] @13200     [0,40400)
    // E view   : bf16 O[256][128B swz] then f32 C[256][128B swz]       [0,32768)

    const int tid = threadIdx.x;

    // XCD-aware swizzle: 2048 blocks, 8 XCDs -> each XCD one batch image
    const int flat = blockIdx.x;
    const int wg   = (flat & 7) * 256 + (flat >> 3);
    const int tx = wg & 15;
    const int ty = (wg >> 4) & 15;
    const int b  = wg >> 8;

    // ---- Phase A ----
    for (int i = tid; i < 1344; i += 256) {
        int kq = i / 112, p = i - kq*112;     // kq: 16B chunk (8 channels)
        u32x4 pack = {0u, 0u, 0u, 0u};
        if (p < 100) {
            int py = p / 10, px = p - py*10;
            int gy = ty*8 - 1 + py, gx = tx*8 - 1 + px;
            bool valid = ((unsigned)gy < 128u) && ((unsigned)gx < 128u);
            if (kq < 8) {
                if (valid) {
                    const float* xp = x + ((size_t)b*64 + kq*8)*HW + gy*WIDTH + gx;
                    #pragma unroll
                    for (int e = 0; e < 4; ++e)
                        pack[e] = cvtpk(xp[(size_t)(2*e)*HW], xp[(size_t)(2*e+1)*HW]);
                }
            } else if (kq == 8) {
                // bf16 flags: ch64=valid(1.0), ch65=pad(1.0)
                pack[0] = valid ? 0x00003f80u : 0x3f800000u;
            }
        }
        *(u32x4*)(smem + p*256 + (((unsigned)(kq*16)) ^ (((unsigned)(p & 7)) << 4))) = pack;
    }
    __syncthreads();

    const int lane = tid & 63;
    const int wv   = tid >> 6;
    const int frow = lane & 15;
    const int kseg = lane >> 4;

    // ---- Phase B: feature GEMM (A=wfb rows=features, B=xA rows=pixels) ----
    const unsigned short* wfs = (const unsigned short*)ws;
    f32x4 accs[11];
    #pragma unroll
    for (int tt = 0; tt < 11; ++tt) {
        int t = wv + 4*tt;
        if (t < 42) {
            int mt = t / 6, nt = t - mt*6;
            int prow = mt*16 + frow;
            const unsigned psw = ((unsigned)(prow & 7)) << 4;
            const unsigned short* wrow = wfs + (nt*16 + frow)*104 + kseg*8;
            f32x4 acc = {0.f, 0.f, 0.f, 0.f};
            #pragma unroll
            for (int kk = 0; kk < 3; ++kk) {
                bshort8 wf = *(const bshort8*)(wrow + kk*32);
                bshort8 xa = *(const bshort8*)(smem + prow*256
                                 + (((unsigned)(kseg*16 + kk*64)) ^ psw));
                acc = __builtin_amdgcn_mfma_f32_16x16x32_bf16(wf, xa, acc, 0, 0, 0);
            }
            accs[tt] = acc;
        }
    }
    __syncthreads();   // xA dead

    // ---- Phase C: scatter (lane owns pixel p, 4 consecutive features) ----
    float* Lbf = (float*)smem;             // [100][33]
    float* Vbf = (float*)(smem + 13200);   // [100][68]
    #pragma unroll
    for (int tt = 0; tt < 11; ++tt) {
        int t = wv + 4*tt;
        if (t < 42) {
            int mt = t / 6, nt = t - mt*6;
            int p = mt*16 + frow;
            if (p < 100) {
                if (nt < 2) {
                    float* lp = Lbf + p*33 + nt*16 + kseg*4;
                    #pragma unroll
                    for (int r = 0; r < 4; ++r) lp[r] = accs[tt][r];
                } else {
                    *(f32x4*)(Vbf + p*68 + (nt-2)*16 + kseg*4) = accs[tt];
                }
            }
        }
    }
    __syncthreads();

    // ---- Phase D: wave = head-pair, lane = pixel, all 4 q ----
    const int dpy = lane >> 3, dpx = lane & 7;
    const int pbase = dpy*10 + dpx;
    const float* relw = ws + REL_OFF;

    unsigned od[32];   // packed bf16 O rows: [(q*2+hh)*4 + j]
    #pragma unroll
    for (int hh = 0; hh < 2; ++hh) {
        const int h = wv*2 + hh;
        // no-max exp2 softmax (logits bounded; 1/sum deferred past PV)
        float l[4][9];
        float rinv[4];
        #pragma unroll
        for (int q = 0; q < 4; ++q) {
            const int hq = h*4 + q;
            const float* Lp = Lbf + pbase*33 + hq;
            const float* rp = relw + hq*9;
            #pragma unroll
            for (int n = 0; n < 9; ++n)
                l[q][n] = exp2f(Lp[((n/3)*10 + (n%3))*33] + rp[n]);
            float s = ((l[q][0]+l[q][1]) + (l[q][2]+l[q][3]))
                    + ((l[q][4]+l[q][5]) + (l[q][6]+l[q][7])) + l[q][8];
            rinv[q] = __builtin_amdgcn_rcpf(s);
        }
        // PV with packed fma; V reads shared across q
        f32x2 o2[4][4];
        #pragma unroll
        for (int q = 0; q < 4; ++q)
            #pragma unroll
            for (int j = 0; j < 4; ++j) o2[q][j] = (f32x2){0.f, 0.f};
        #pragma unroll
        for (int n = 0; n < 9; ++n) {
            const float* vp = Vbf + (pbase + (n/3)*10 + (n%3))*68 + h*8;
            const f32x4 v0 = *(const f32x4*)vp;
            const f32x4 v1 = *(const f32x4*)(vp + 4);
            const f32x2 w0 = __builtin_shufflevector(v0, v0, 0, 1);
            const f32x2 w1 = __builtin_shufflevector(v0, v0, 2, 3);
            const f32x2 w2 = __builtin_shufflevector(v1, v1, 0, 1);
            const f32x2 w3 = __builtin_shufflevector(v1, v1, 2, 3);
            #pragma unroll
            for (int q = 0; q < 4; ++q) {
                const f32x2 a2 = {l[q][n], l[q][n]};
                o2[q][0] = pkfma(o2[q][0], a2, w0);
                o2[q][1] = pkfma(o2[q][1], a2, w1);
                o2[q][2] = pkfma(o2[q][2], a2, w2);
                o2[q][3] = pkfma(o2[q][3], a2, w3);
            }
        }
        #pragma unroll
        for (int q = 0; q < 4; ++q) {
            const f32x2 r2 = {rinv[q], rinv[q]};
            #pragma unroll
            for (int j = 0; j < 4; ++j) {
                const f32x2 s = pkmul(o2[q][j], r2);
                od[(q*2 + hh)*4 + j] = cvtpk(s[0], s[1]);
            }
        }
    }
    __syncthreads();   // Lbf/Vbf dead

    // O-writes: row = lane*4+q (128B rows, off ^= ((row>>2)&7)<<4 = (lane&7)<<4)
    {
        const unsigned sw = ((unsigned)(lane & 7)) << 4;
        #pragma unroll
        for (int q = 0; q < 4; ++q) {
            const int row = lane*4 + q;
            #pragma unroll
            for (int hh = 0; hh < 2; ++hh) {
                u32x4 w4 = { od[(q*2+hh)*4+0], od[(q*2+hh)*4+1],
                             od[(q*2+hh)*4+2], od[(q*2+hh)*4+3] };
                *(u32x4*)(smem + row*128 + (((unsigned)(wv*32 + hh*16)) ^ sw)) = w4;
            }
        }
    }
    __syncthreads();   // O complete (cross-wave)

    // ---- Phase E: Wo via MFMA; wave wv owns rows [wv*64, wv*64+64) ----
    const unsigned short* wot = wfs + WFB_DWORDS*2;
    bshort8 av[4][2];
    #pragma unroll
    for (int mt = 0; mt < 4; ++mt) {
        const int row = wv*64 + mt*16 + frow;
        const unsigned sw = (((unsigned)(row >> 2)) & 7u) << 4;
        #pragma unroll
        for (int ks = 0; ks < 2; ++ks)
            av[mt][ks] = *(const bshort8*)(smem + row*128
                             + (((unsigned)(kseg*16 + ks*64)) ^ sw));
    }
    bshort8 bv_[2][2];
    #pragma unroll
    for (int nt = 0; nt < 2; ++nt) {
        const int col = nt*16 + frow;
        #pragma unroll
        for (int ks = 0; ks < 2; ++ks)
            bv_[nt][ks] = *(const bshort8*)(wot + col*64 + kseg*8 + ks*32);
    }
    f32x4 cacc[4][2];
    #pragma unroll
    for (int mt = 0; mt < 4; ++mt)
        #pragma unroll
        for (int nt = 0; nt < 2; ++nt)
            cacc[mt][nt] = (f32x4){0.f, 0.f, 0.f, 0.f};
    #pragma unroll
    for (int ks = 0; ks < 2; ++ks)
        #pragma unroll
        for (int mt = 0; mt < 4; ++mt)
            #pragma unroll
            for (int nt = 0; nt < 2; ++nt)
                cacc[mt][nt] = __builtin_amdgcn_mfma_f32_16x16x32_bf16(
                    av[mt][ks], bv_[nt][ks], cacc[mt][nt], 0, 0, 0);

    // C-write into own 8KB slice (only own wave reads)
    #pragma unroll
    for (int mt = 0; mt < 4; ++mt)
        #pragma unroll
        for (int nt = 0; nt < 2; ++nt)
            #pragma unroll
            for (int r = 0; r < 4; ++r) {
                const int row = wv*64 + mt*16 + kseg*4 + r;
                const int col = nt*16 + frow;
                *(float*)(smem + row*128
                    + (((unsigned)(col*4)) ^ ((((unsigned)(row >> 2)) & 7u) << 4)))
                    = cacc[mt][nt][r];
            }
    asm volatile("s_waitcnt lgkmcnt(0)" ::: "memory");

    // C-read own row (= tid), add bo, LN, pixel-shuffle store
    float cv[32];
    {
        const unsigned sw = (((unsigned)(tid >> 2)) & 7u) << 4;
        #pragma unroll
        for (int j = 0; j < 8; ++j) {
            const f32x4 c4 = *(const f32x4*)(smem + tid*128 + (((unsigned)(j*16)) ^ sw));
            cv[j*4+0] = c4[0]; cv[j*4+1] = c4[1]; cv[j*4+2] = c4[2]; cv[j*4+3] = c4[3];
        }
    }
    float mu = 0.f;
    #pragma unroll
    for (int oc = 0; oc < 32; ++oc) { cv[oc] += bo[oc]; mu += cv[oc]; }
    mu *= (1.f/32.f);
    float var = 0.f;
    #pragma unroll
    for (int oc = 0; oc < 32; ++oc) { float d = cv[oc] - mu; var += d*d; }
    var *= (1.f/32.f);
    const float rstd = rsqrtf(var + 1e-5f);

    const int q   = tid & 3;
    const int pix = tid >> 2;
    const int gy = ty*8 + (pix >> 3), gx = tx*8 + (pix & 7);
    const int Y = gy*2 + (q >> 1), X = gx*2 + (q & 1);
    float* op = out + (((size_t)b*32)*256 + Y)*256 + X;
    #pragma unroll
    for (int oc = 0; oc < 32; ++oc) {
        float v = (cv[oc] - mu) * rstd * ln_g[oc] + ln_b[oc];
        op[(size_t)oc * 65536] = v;
    }
}

// ---------------------------------------------------------------------------
extern "C" void kernel_launch(void* const* d_in, const int* in_sizes, int n_in,
                              void* d_out, int out_size, void* d_ws, size_t ws_size,
                              hipStream_t stream)
{
    const float* x        = (const float*)d_in[0];
    const float* up_query = (const float*)d_in[1];
    const float* Wk  = (const float*)d_in[2];
    const float* bk  = (const float*)d_in[3];
    const float* Wv  = (const float*)d_in[4];
    const float* bv  = (const float*)d_in[5];
    const float* Wq  = (const float*)d_in[6];
    const float* bq  = (const float*)d_in[7];
    const float* Wka = (const float*)d_in[8];
    const float* bka = (const float*)d_in[9];
    const float* Wva = (const float*)d_in[10];
    const float* bva = (const float*)d_in[11];
    const float* Wo  = (const float*)d_in[12];
    const float* bo  = (const float*)d_in[13];
    const float* rel_pos = (const float*)d_in[14];
    const float* ln_g = (const float*)d_in[15];
    const float* ln_b = (const float*)d_in[16];

    float* ws  = (float*)d_ws;
    float* out = (float*)d_out;

    if (ws_size < (size_t)(REL_OFF + 288) * 4) return;

    k0_fuse<<<1, 256, 0, stream>>>(up_query, Wk, bk, Wv, bv, Wq, bq,
                                   Wka, bka, Wva, bva, Wo, rel_pos, ws);
    k2_attn<<<2048, 256, 0, stream>>>(x, ws, bo, ln_g, ln_b, out);
}

// Round 7
// 63.882 us; speedup vs baseline: 3.3412x; 1.6142x over previous
//
#include <hip/hip_runtime.h>

// Problem constants
#define HW    16384   // 128*128
#define WIDTH 128
#define LOG2E    1.4426950408889634f
#define RS_LOG2E 0.5101464200926166f   // (1/sqrt(8)) * LOG2E

// ws layout (dwords):
//  [0, 4992):     wfb — bf16 [96][104] fused feature B-matrix (logit rows pre-scaled by LOG2E)
//  [4992, 6016):  wot — fp16 [32 col][64 k] Wo^T for the epilogue MFMA
//  [6016, 6304):  rel — f32 [32][9], pre-scaled by LOG2E
#define WFB_DWORDS 4992
#define WOT_DWORDS 1024
#define REL_OFF    (WFB_DWORDS + WOT_DWORDS)

typedef short bshort8 __attribute__((ext_vector_type(8)));
typedef _Float16 half8 __attribute__((ext_vector_type(8)));
typedef float f32x4   __attribute__((ext_vector_type(4)));
typedef unsigned u32x4 __attribute__((ext_vector_type(4)));
typedef unsigned u32x2 __attribute__((ext_vector_type(2)));

static __device__ inline unsigned short f2bf(float f) {
    unsigned u = __builtin_bit_cast(unsigned, f);
    unsigned r = u + 0x7fff + ((u >> 16) & 1);   // RNE
    return (unsigned short)(r >> 16);
}
static __device__ inline unsigned cvtpk(float lo, float hi) {  // 2xf32 -> packed bf16
    unsigned d;
    asm("v_cvt_pk_bf16_f32 %0, %1, %2" : "=v"(d) : "v"(lo), "v"(hi));
    return d;
}
static __device__ inline unsigned pkrtz(float lo, float hi) {  // 2xf32 -> packed fp16
    return __builtin_bit_cast(unsigned, __builtin_amdgcn_cvt_pkrtz(lo, hi));
}
// o += bcast(a) * v   (fp16 pairs; a's lo or hi half broadcast to both lanes)
static __device__ inline unsigned pkfma16_lo(unsigned o, unsigned a, unsigned v) {
    asm("v_pk_fma_f16 %0, %1, %2, %0 op_sel:[0,0,0] op_sel_hi:[0,1,1]"
        : "+v"(o) : "v"(a), "v"(v));
    return o;
}
static __device__ inline unsigned pkfma16_hi(unsigned o, unsigned a, unsigned v) {
    asm("v_pk_fma_f16 %0, %1, %2, %0 op_sel:[1,0,0] op_sel_hi:[1,1,1]"
        : "+v"(o) : "v"(a), "v"(v));
    return o;
}
// d = a * bcast(r)
static __device__ inline unsigned pkmul16_lo(unsigned a, unsigned r) {
    unsigned d;
    asm("v_pk_mul_f16 %0, %1, %2 op_sel:[0,0] op_sel_hi:[0,1]"
        : "=v"(d) : "v"(r), "v"(a));
    return d;
}
static __device__ inline unsigned pkmul16_hi(unsigned a, unsigned r) {
    unsigned d;
    asm("v_pk_mul_f16 %0, %1, %2 op_sel:[1,0] op_sel_hi:[1,1]"
        : "=v"(d) : "v"(r), "v"(a));
    return d;
}

// ---------------------------------------------------------------------------
// K0: fold weights — 8 blocks, each owns 12 feature rows of wfb.
//     WL = Wk @ tq  (tq = per-(h,q) Wka@qc slices) — never materializes Wk@Wka.
// ---------------------------------------------------------------------------
__global__ __launch_bounds__(256) void k0_fuse(
    const float* __restrict__ up_query,
    const float* __restrict__ Wk, const float* __restrict__ bk,
    const float* __restrict__ Wv, const float* __restrict__ bv,
    const float* __restrict__ Wq, const float* __restrict__ bq,
    const float* __restrict__ Wka, const float* __restrict__ bka,
    const float* __restrict__ Wva, const float* __restrict__ bva,
    const float* __restrict__ Wo, const float* __restrict__ rel_pos,
    float* __restrict__ ws)
{
    __shared__ float qcS[4][64];
    __shared__ float WkT[64][65];   // [e][c] transposed
    __shared__ float WvT[64][65];
    __shared__ float colS[12][64];  // per-j K-column (tq*RS_LOG2E or Wva col)
    __shared__ float bred[12][8];
    __shared__ float pred[12][8];

    const int tid = threadIdx.x;
    const int bj  = blockIdx.x;     // 0..7
    const int j0  = bj * 12;

    // qc[q][f] = up_query@Wq + bq  (256 jobs)
    {
        int q = tid >> 6, f = tid & 63;
        float a = bq[f];
        for (int c = 0; c < 64; ++c) a = fmaf(up_query[q*64+c], Wq[c*64+f], a);
        qcS[q][f] = a;
    }
    // stage transposed Wk / Wv
    for (int i = tid; i < 4096; i += 256) {
        int c = i >> 6, e = i & 63;
        WkT[e][c] = Wk[i];
        WvT[e][c] = Wv[i];
    }
    __syncthreads();

    // colS: 768 jobs (12 j x 64 e)
    for (int i = tid; i < 768; i += 256) {
        int jl = i >> 6, e = i & 63;
        int j = j0 + jl;
        float v;
        if (j < 32) {
            int h = j >> 2, qq = j & 3;
            float s = 0.f;
            #pragma unroll
            for (int d = 0; d < 8; ++d)
                s = fmaf(Wka[e*64 + h*8 + d], qcS[qq][h*8 + d], s);
            v = s * RS_LOG2E;
        } else {
            v = Wva[e*64 + (j - 32)];
        }
        colS[jl][e] = v;
    }
    // bias partials: 96 jobs (12 j x 8 d)
    if (tid < 96) {
        int jl = tid >> 3, d = tid & 7;
        int j = j0 + jl;
        if (j < 32) {
            int h = j >> 2, qq = j & 3;
            int fi = h*8 + d;
            float bW = 0.f;
            for (int e = 0; e < 64; ++e) bW = fmaf(bk[e], Wka[e*64 + fi], bW);
            float qv = qcS[qq][fi];
            bred[jl][d] = (2.f*bW + bka[fi]) * qv;   // valid-position part
            pred[jl][d] = bW * qv;                   // valid - pad difference
        } else {
            float s = 0.f;
            for (int e = d*8; e < d*8 + 8; ++e)
                s = fmaf(bv[e], Wva[e*64 + (j - 32)], s);
            bred[jl][d] = s;
            pred[jl][d] = 0.f;
        }
    }
    __syncthreads();

    unsigned* wsd = (unsigned*)ws;
    // main GEMM + emit: 384 jobs (32 c-pairs x 12 j)
    for (int i = tid; i < 384; i += 256) {
        int cp = i & 31, jl = i >> 5;
        int j = j0 + jl;
        const float (*MT)[65] = (j < 32) ? WkT : WvT;
        float o0 = 0.f, o1 = 0.f;
        for (int e = 0; e < 64; ++e) {
            float cv = colS[jl][e];
            o0 = fmaf(MT[e][2*cp],     cv, o0);
            o1 = fmaf(MT[e][2*cp + 1], cv, o1);
        }
        wsd[j*52 + cp] = (unsigned)f2bf(o0) | ((unsigned)f2bf(o1) << 16);
    }
    // bias dword (kd=32) + zero cols (kd 33..51): 12 x 20 jobs
    for (int i = tid; i < 240; i += 256) {
        int jl = i / 20, kd = 32 + (i % 20);
        int j = j0 + jl;
        unsigned val = 0u;
        if (kd == 32) {
            float sv = 0.f, sp = 0.f;
            #pragma unroll
            for (int d = 0; d < 8; ++d) { sv += bred[jl][d]; sp += pred[jl][d]; }
            float bf_, pd_;
            if (j < 32) { bf_ = sv * RS_LOG2E; pd_ = (sv - sp) * RS_LOG2E; }
            else        { bf_ = sv + bva[j-32]; pd_ = bva[j-32]; }
            val = (unsigned)f2bf(bf_) | ((unsigned)f2bf(pd_) << 16);
        }
        wsd[j*52 + kd] = val;
    }
    // wot (fp16) + rel: block 7
    if (bj == 7) {
        for (int i = tid; i < WOT_DWORDS; i += 256) {
            int col = i >> 5, kp = i & 31;
            wsd[WFB_DWORDS + i] = pkrtz(Wo[(2*kp)*32 + col], Wo[(2*kp + 1)*32 + col]);
        }
        for (int i = tid; i < 288; i += 256)
            ws[REL_OFF + i] = rel_pos[i] * LOG2E;
    }
}

// ---------------------------------------------------------------------------
// K2: fused pipeline, LDS = 32768 -> 5 blocks/CU.
//  A: stage 10x10 x-halo bf16 into xA[112 rows][256B] (XOR-swizzled)
//  B: MFMA bf16 feature GEMM (A=wfb, B=xA): lane holds 4 consecutive feats/pixel
//  C: scatter fp16 -> Lh[100][36]u16, Vh[100][72]u16 (pkrtz, b64 writes)
//  D: wave = head-pair, lane = pixel: no-max exp2 softmax, PV accum fp16 via
//     v_pk_fma_f16 op_sel-broadcast, deferred 1/sum via v_pk_mul_f16
//  E: O fp16 [256][128B swz] -> mfma f16 x WoT -> C f32 -> LN -> store
// ---------------------------------------------------------------------------
__global__ __launch_bounds__(256, 5) void k2_attn(
    const float* __restrict__ x, const float* __restrict__ ws,
    const float* __restrict__ bo,
    const float* __restrict__ ln_g, const float* __restrict__ ln_b,
    float* __restrict__ out)
{
    __shared__ __align__(16) char smem[32768];
    // A/B : bf16 xA rows p=0..111, 256B stride, byte ^= (p&7)<<4     [0,28672)
    // C/D : fp16 Lh[100][36] @0 (7200B); fp16 Vh[100][72] @8192 (14400B)
    // E   : fp16 O[256][128B swz] then f32 C in place                [0,32768)

    const int tid = threadIdx.x;

    // XCD-aware swizzle: 2048 blocks, 8 XCDs -> each XCD one batch image
    const int flat = blockIdx.x;
    const int wg   = (flat & 7) * 256 + (flat >> 3);
    const int tx = wg & 15;
    const int ty = (wg >> 4) & 15;
    const int b  = wg >> 8;

    // ---- Phase A: division-free mapping p=i&127, kq=i>>7 (12 chunks x 16B) ----
    #pragma unroll
    for (int it = 0; it < 6; ++it) {
        int i = tid + it*256;
        int p = i & 127, kq = i >> 7;
        if (p < 112) {
            u32x4 pack = {0u, 0u, 0u, 0u};
            if (p < 100) {
                int py = p / 10, px = p - py*10;
                int gy = ty*8 - 1 + py, gx = tx*8 - 1 + px;
                bool valid = ((unsigned)gy < 128u) && ((unsigned)gx < 128u);
                if (kq < 8) {
                    if (valid) {
                        const float* xp = x + ((size_t)b*64 + kq*8)*HW + gy*WIDTH + gx;
                        #pragma unroll
                        for (int e = 0; e < 4; ++e)
                            pack[e] = cvtpk(xp[(size_t)(2*e)*HW], xp[(size_t)(2*e+1)*HW]);
                    }
                } else if (kq == 8) {
                    pack[0] = valid ? 0x00003f80u : 0x3f800000u;  // bf16 flags
                }
            }
            *(u32x4*)(smem + p*256 + (((unsigned)(kq*16)) ^ (((unsigned)(p & 7)) << 4))) = pack;
        }
    }
    __syncthreads();

    const int lane = tid & 63;
    const int wv   = tid >> 6;
    const int frow = lane & 15;
    const int kseg = lane >> 4;

    // ---- Phase B: bf16 feature GEMM ----
    const unsigned short* wfs = (const unsigned short*)ws;
    f32x4 accs[11];
    #pragma unroll
    for (int tt = 0; tt < 11; ++tt) {
        int t = wv + 4*tt;
        if (t < 42) {
            int mt = t / 6, nt = t - mt*6;
            int prow = mt*16 + frow;
            const unsigned psw = ((unsigned)(prow & 7)) << 4;
            const unsigned short* wrow = wfs + (nt*16 + frow)*104 + kseg*8;
            f32x4 acc = {0.f, 0.f, 0.f, 0.f};
            #pragma unroll
            for (int kk = 0; kk < 3; ++kk) {
                bshort8 wf = *(const bshort8*)(wrow + kk*32);
                bshort8 xa = *(const bshort8*)(smem + prow*256
                                 + (((unsigned)(kseg*16 + kk*64)) ^ psw));
                acc = __builtin_amdgcn_mfma_f32_16x16x32_bf16(wf, xa, acc, 0, 0, 0);
            }
            accs[tt] = acc;
        }
    }
    __syncthreads();   // xA dead

    // ---- Phase C: fp16 scatter ----
    unsigned short* Lh = (unsigned short*)smem;            // [100][36]
    unsigned short* Vh = (unsigned short*)(smem + 8192);   // [100][72]
    #pragma unroll
    for (int tt = 0; tt < 11; ++tt) {
        int t = wv + 4*tt;
        if (t < 42) {
            int mt = t / 6, nt = t - mt*6;
            int p = mt*16 + frow;
            if (p < 100) {
                u32x2 dd = { pkrtz(accs[tt][0], accs[tt][1]),
                             pkrtz(accs[tt][2], accs[tt][3]) };
                if (nt < 2) *(u32x2*)(Lh + p*36 + nt*16 + kseg*4) = dd;
                else        *(u32x2*)(Vh + p*72 + (nt-2)*16 + kseg*4) = dd;
            }
        }
    }
    __syncthreads();

    // ---- Phase D: wave = head-pair, lane = pixel, all 4 q ----
    const int dpy = lane >> 3, dpx = lane & 7;
    const int pbase = dpy*10 + dpx;
    const float* relw = ws + REL_OFF;

    unsigned od[32];   // packed fp16 O rows: [(q*2+hh)*4 + j]
    #pragma unroll
    for (int hh = 0; hh < 2; ++hh) {
        const int h = wv*2 + hh;
        unsigned apk[2][9];
        float rinv[4];
        #pragma unroll
        for (int qp = 0; qp < 2; ++qp) {
            const int hq0 = h*4 + qp*2;
            float l0[9], l1[9];
            #pragma unroll
            for (int n = 0; n < 9; ++n) {
                const int off = (n/3)*10 + (n%3);
                l0[n] = exp2f((float)*(const _Float16*)(Lh + (pbase+off)*36 + hq0)
                              + relw[hq0*9 + n]);
                l1[n] = exp2f((float)*(const _Float16*)(Lh + (pbase+off)*36 + hq0 + 1)
                              + relw[(hq0+1)*9 + n]);
            }
            float s0 = ((l0[0]+l0[1]) + (l0[2]+l0[3]))
                     + ((l0[4]+l0[5]) + (l0[6]+l0[7])) + l0[8];
            float s1 = ((l1[0]+l1[1]) + (l1[2]+l1[3]))
                     + ((l1[4]+l1[5]) + (l1[6]+l1[7])) + l1[8];
            rinv[qp*2]     = __builtin_amdgcn_rcpf(s0);
            rinv[qp*2 + 1] = __builtin_amdgcn_rcpf(s1);
            #pragma unroll
            for (int n = 0; n < 9; ++n) apk[qp][n] = pkrtz(l0[n], l1[n]);
        }
        unsigned o16[4][4] = {{0u,0u,0u,0u},{0u,0u,0u,0u},{0u,0u,0u,0u},{0u,0u,0u,0u}};
        #pragma unroll
        for (int n = 0; n < 9; ++n) {
            const int off = (n/3)*10 + (n%3);
            const u32x4 v4 = *(const u32x4*)(Vh + (pbase + off)*72 + h*8);
            #pragma unroll
            for (int j = 0; j < 4; ++j) {
                o16[0][j] = pkfma16_lo(o16[0][j], apk[0][n], v4[j]);
                o16[1][j] = pkfma16_hi(o16[1][j], apk[0][n], v4[j]);
                o16[2][j] = pkfma16_lo(o16[2][j], apk[1][n], v4[j]);
                o16[3][j] = pkfma16_hi(o16[3][j], apk[1][n], v4[j]);
            }
        }
        const unsigned r01 = pkrtz(rinv[0], rinv[1]);
        const unsigned r23 = pkrtz(rinv[2], rinv[3]);
        #pragma unroll
        for (int j = 0; j < 4; ++j) {
            od[(0*2 + hh)*4 + j] = pkmul16_lo(o16[0][j], r01);
            od[(1*2 + hh)*4 + j] = pkmul16_hi(o16[1][j], r01);
            od[(2*2 + hh)*4 + j] = pkmul16_lo(o16[2][j], r23);
            od[(3*2 + hh)*4 + j] = pkmul16_hi(o16[3][j], r23);
        }
    }
    __syncthreads();   // Lh/Vh dead

    // O-writes: row = lane*4+q (128B rows, byte ^= ((row>>2)&7)<<4 = (lane&7)<<4)
    {
        const unsigned sw = ((unsigned)(lane & 7)) << 4;
        #pragma unroll
        for (int q = 0; q < 4; ++q) {
            const int row = lane*4 + q;
            #pragma unroll
            for (int hh = 0; hh < 2; ++hh) {
                u32x4 w4 = { od[(q*2+hh)*4+0], od[(q*2+hh)*4+1],
                             od[(q*2+hh)*4+2], od[(q*2+hh)*4+3] };
                *(u32x4*)(smem + row*128 + (((unsigned)(wv*32 + hh*16)) ^ sw)) = w4;
            }
        }
    }
    __syncthreads();   // O complete (cross-wave)

    // ---- Phase E: Wo via fp16 MFMA; wave wv owns rows [wv*64, wv*64+64) ----
    const unsigned short* wotu = (const unsigned short*)ws + WFB_DWORDS*2;
    half8 av[4][2];
    #pragma unroll
    for (int mt = 0; mt < 4; ++mt) {
        const int row = wv*64 + mt*16 + frow;
        const unsigned sw = (((unsigned)(row >> 2)) & 7u) << 4;
        #pragma unroll
        for (int ks = 0; ks < 2; ++ks)
            av[mt][ks] = __builtin_bit_cast(half8,
                *(const u32x4*)(smem + row*128 + (((unsigned)(kseg*16 + ks*64)) ^ sw)));
    }
    half8 bv_[2][2];
    #pragma unroll
    for (int nt = 0; nt < 2; ++nt) {
        const int col = nt*16 + frow;
        #pragma unroll
        for (int ks = 0; ks < 2; ++ks)
            bv_[nt][ks] = __builtin_bit_cast(half8,
                *(const u32x4*)(wotu + col*64 + kseg*8 + ks*32));
    }
    f32x4 cacc[4][2];
    #pragma unroll
    for (int mt = 0; mt < 4; ++mt)
        #pragma unroll
        for (int nt = 0; nt < 2; ++nt)
            cacc[mt][nt] = (f32x4){0.f, 0.f, 0.f, 0.f};
    #pragma unroll
    for (int ks = 0; ks < 2; ++ks)
        #pragma unroll
        for (int mt = 0; mt < 4; ++mt)
            #pragma unroll
            for (int nt = 0; nt < 2; ++nt)
                cacc[mt][nt] = __builtin_amdgcn_mfma_f32_16x16x32_f16(
                    av[mt][ks], bv_[nt][ks], cacc[mt][nt], 0, 0, 0);

    // C-write f32 into own 8KB slice (only own wave reads)
    #pragma unroll
    for (int mt = 0; mt < 4; ++mt)
        #pragma unroll
        for (int nt = 0; nt < 2; ++nt)
            #pragma unroll
            for (int r = 0; r < 4; ++r) {
                const int row = wv*64 + mt*16 + kseg*4 + r;
                const int col = nt*16 + frow;
                *(float*)(smem + row*128
                    + (((unsigned)(col*4)) ^ ((((unsigned)(row >> 2)) & 7u) << 4)))
                    = cacc[mt][nt][r];
            }
    asm volatile("s_waitcnt lgkmcnt(0)" ::: "memory");

    // C-read own row (= tid), add bo, LN, pixel-shuffle store
    float cv[32];
    {
        const unsigned sw = (((unsigned)(tid >> 2)) & 7u) << 4;
        #pragma unroll
        for (int j = 0; j < 8; ++j) {
            const f32x4 c4 = *(const f32x4*)(smem + tid*128 + (((unsigned)(j*16)) ^ sw));
            cv[j*4+0] = c4[0]; cv[j*4+1] = c4[1]; cv[j*4+2] = c4[2]; cv[j*4+3] = c4[3];
        }
    }
    float mu = 0.f;
    #pragma unroll
    for (int oc = 0; oc < 32; ++oc) { cv[oc] += bo[oc]; mu += cv[oc]; }
    mu *= (1.f/32.f);
    float var = 0.f;
    #pragma unroll
    for (int oc = 0; oc < 32; ++oc) { float d = cv[oc] - mu; var += d*d; }
    var *= (1.f/32.f);
    const float rstd = rsqrtf(var + 1e-5f);

    const int q   = tid & 3;
    const int pix = tid >> 2;
    const int gy = ty*8 + (pix >> 3), gx = tx*8 + (pix & 7);
    const int Y = gy*2 + (q >> 1), X = gx*2 + (q & 1);
    float* op = out + (((size_t)b*32)*256 + Y)*256 + X;
    #pragma unroll
    for (int oc = 0; oc < 32; ++oc) {
        float v = (cv[oc] - mu) * rstd * ln_g[oc] + ln_b[oc];
        op[(size_t)oc * 65536] = v;
    }
}

// ---------------------------------------------------------------------------
extern "C" void kernel_launch(void* const* d_in, const int* in_sizes, int n_in,
                              void* d_out, int out_size, void* d_ws, size_t ws_size,
                              hipStream_t stream)
{
    const float* x        = (const float*)d_in[0];
    const float* up_query = (const float*)d_in[1];
    const float* Wk  = (const float*)d_in[2];
    const float* bk  = (const float*)d_in[3];
    const float* Wv  = (const float*)d_in[4];
    const float* bv  = (const float*)d_in[5];
    const float* Wq  = (const float*)d_in[6];
    const float* bq  = (const float*)d_in[7];
    const float* Wka = (const float*)d_in[8];
    const float* bka = (const float*)d_in[9];
    const float* Wva = (const float*)d_in[10];
    const float* bva = (const float*)d_in[11];
    const float* Wo  = (const float*)d_in[12];
    const float* bo  = (const float*)d_in[13];
    const float* rel_pos = (const float*)d_in[14];
    const float* ln_g = (const float*)d_in[15];
    const float* ln_b = (const float*)d_in[16];

    float* ws  = (float*)d_ws;
    float* out = (float*)d_out;

    if (ws_size < (size_t)(REL_OFF + 288) * 4) return;

    k0_fuse<<<8, 256, 0, stream>>>(up_query, Wk, bk, Wv, bv, Wq, bq,
                                   Wka, bka, Wva, bva, Wo, rel_pos, ws);
    k2_attn<<<2048, 256, 0, stream>>>(x, ws, bo, ln_g, ln_b, out);
}

// Round 8
// 62.344 us; speedup vs baseline: 3.4237x; 1.0247x over previous
//
#include <hip/hip_runtime.h>

// Problem constants
#define HW    16384   // 128*128
#define WIDTH 128
#define LOG2E    1.4426950408889634f
#define RS_LOG2E 0.5101464200926166f   // (1/sqrt(8)) * LOG2E

// ws layout (dwords):
//  [0, 4992):     wfb — bf16 [96][104] fused feature B-matrix (logit rows pre-scaled by LOG2E)
//  [4992, 6016):  wot — fp16 [32 col][64 k] Wo^T for the epilogue MFMA
//  [6016, 6304):  rel — f32 [32][9], pre-scaled by LOG2E
#define WFB_DWORDS 4992
#define WOT_DWORDS 1024
#define REL_OFF    (WFB_DWORDS + WOT_DWORDS)

typedef short bshort8 __attribute__((ext_vector_type(8)));
typedef _Float16 half8 __attribute__((ext_vector_type(8)));
typedef float f32x4   __attribute__((ext_vector_type(4)));
typedef unsigned u32x4 __attribute__((ext_vector_type(4)));
typedef unsigned u32x2 __attribute__((ext_vector_type(2)));

static __device__ inline unsigned short f2bf(float f) {
    unsigned u = __builtin_bit_cast(unsigned, f);
    unsigned r = u + 0x7fff + ((u >> 16) & 1);   // RNE
    return (unsigned short)(r >> 16);
}
static __device__ inline unsigned cvtpk(float lo, float hi) {  // 2xf32 -> packed bf16
    unsigned d;
    asm("v_cvt_pk_bf16_f32 %0, %1, %2" : "=v"(d) : "v"(lo), "v"(hi));
    return d;
}
static __device__ inline unsigned pkrtz(float lo, float hi) {  // 2xf32 -> packed fp16
    return __builtin_bit_cast(unsigned, __builtin_amdgcn_cvt_pkrtz(lo, hi));
}
static __device__ inline float lo16f(unsigned u) {
    return (float)__builtin_bit_cast(_Float16, (unsigned short)(u & 0xffffu));
}
static __device__ inline float hi16f(unsigned u) {
    return (float)__builtin_bit_cast(_Float16, (unsigned short)(u >> 16));
}
// o += bcast(a.lo/hi) * v   (fp16 pairs)
static __device__ inline unsigned pkfma16_lo(unsigned o, unsigned a, unsigned v) {
    asm("v_pk_fma_f16 %0, %1, %2, %0 op_sel:[0,0,0] op_sel_hi:[0,1,1]"
        : "+v"(o) : "v"(a), "v"(v));
    return o;
}
static __device__ inline unsigned pkfma16_hi(unsigned o, unsigned a, unsigned v) {
    asm("v_pk_fma_f16 %0, %1, %2, %0 op_sel:[1,0,0] op_sel_hi:[1,1,1]"
        : "+v"(o) : "v"(a), "v"(v));
    return o;
}
// d = a * bcast(r.lo/hi)
static __device__ inline unsigned pkmul16_lo(unsigned a, unsigned r) {
    unsigned d;
    asm("v_pk_mul_f16 %0, %1, %2 op_sel:[0,0] op_sel_hi:[0,1]"
        : "=v"(d) : "v"(r), "v"(a));
    return d;
}
static __device__ inline unsigned pkmul16_hi(unsigned a, unsigned r) {
    unsigned d;
    asm("v_pk_mul_f16 %0, %1, %2 op_sel:[1,0] op_sel_hi:[1,1]"
        : "=v"(d) : "v"(r), "v"(a));
    return d;
}

// ---------------------------------------------------------------------------
// K0: fold weights — 8 blocks, each owns 12 feature rows of wfb.
// ---------------------------------------------------------------------------
__global__ __launch_bounds__(256) void k0_fuse(
    const float* __restrict__ up_query,
    const float* __restrict__ Wk, const float* __restrict__ bk,
    const float* __restrict__ Wv, const float* __restrict__ bv,
    const float* __restrict__ Wq, const float* __restrict__ bq,
    const float* __restrict__ Wka, const float* __restrict__ bka,
    const float* __restrict__ Wva, const float* __restrict__ bva,
    const float* __restrict__ Wo, const float* __restrict__ rel_pos,
    float* __restrict__ ws)
{
    __shared__ float qcS[4][64];
    __shared__ float WkT[64][65];   // [e][c] transposed
    __shared__ float WvT[64][65];
    __shared__ float colS[12][64];  // per-j K-column (tq*RS_LOG2E or Wva col)
    __shared__ float bred[12][8];
    __shared__ float pred[12][8];

    const int tid = threadIdx.x;
    const int bj  = blockIdx.x;     // 0..7
    const int j0  = bj * 12;

    // qc[q][f] = up_query@Wq + bq  (256 jobs)
    {
        int q = tid >> 6, f = tid & 63;
        float a = bq[f];
        for (int c = 0; c < 64; ++c) a = fmaf(up_query[q*64+c], Wq[c*64+f], a);
        qcS[q][f] = a;
    }
    // stage transposed Wk / Wv
    for (int i = tid; i < 4096; i += 256) {
        int c = i >> 6, e = i & 63;
        WkT[e][c] = Wk[i];
        WvT[e][c] = Wv[i];
    }
    __syncthreads();

    // colS: 768 jobs (12 j x 64 e)
    for (int i = tid; i < 768; i += 256) {
        int jl = i >> 6, e = i & 63;
        int j = j0 + jl;
        float v;
        if (j < 32) {
            int h = j >> 2, qq = j & 3;
            float s = 0.f;
            #pragma unroll
            for (int d = 0; d < 8; ++d)
                s = fmaf(Wka[e*64 + h*8 + d], qcS[qq][h*8 + d], s);
            v = s * RS_LOG2E;
        } else {
            v = Wva[e*64 + (j - 32)];
        }
        colS[jl][e] = v;
    }
    // bias partials: 96 jobs (12 j x 8 d)
    if (tid < 96) {
        int jl = tid >> 3, d = tid & 7;
        int j = j0 + jl;
        if (j < 32) {
            int h = j >> 2, qq = j & 3;
            int fi = h*8 + d;
            float bW = 0.f;
            for (int e = 0; e < 64; ++e) bW = fmaf(bk[e], Wka[e*64 + fi], bW);
            float qv = qcS[qq][fi];
            bred[jl][d] = (2.f*bW + bka[fi]) * qv;   // valid-position part
            pred[jl][d] = bW * qv;                   // valid - pad difference
        } else {
            float s = 0.f;
            for (int e = d*8; e < d*8 + 8; ++e)
                s = fmaf(bv[e], Wva[e*64 + (j - 32)], s);
            bred[jl][d] = s;
            pred[jl][d] = 0.f;
        }
    }
    __syncthreads();

    unsigned* wsd = (unsigned*)ws;
    // main GEMM + emit: 384 jobs (32 c-pairs x 12 j)
    for (int i = tid; i < 384; i += 256) {
        int cp = i & 31, jl = i >> 5;
        int j = j0 + jl;
        const float (*MT)[65] = (j < 32) ? WkT : WvT;
        float o0 = 0.f, o1 = 0.f;
        for (int e = 0; e < 64; ++e) {
            float cv = colS[jl][e];
            o0 = fmaf(MT[e][2*cp],     cv, o0);
            o1 = fmaf(MT[e][2*cp + 1], cv, o1);
        }
        wsd[j*52 + cp] = (unsigned)f2bf(o0) | ((unsigned)f2bf(o1) << 16);
    }
    // bias dword (kd=32) + zero cols (kd 33..51): 12 x 20 jobs
    for (int i = tid; i < 240; i += 256) {
        int jl = i / 20, kd = 32 + (i % 20);
        int j = j0 + jl;
        unsigned val = 0u;
        if (kd == 32) {
            float sv = 0.f, sp = 0.f;
            #pragma unroll
            for (int d = 0; d < 8; ++d) { sv += bred[jl][d]; sp += pred[jl][d]; }
            float bf_, pd_;
            if (j < 32) { bf_ = sv * RS_LOG2E; pd_ = (sv - sp) * RS_LOG2E; }
            else        { bf_ = sv + bva[j-32]; pd_ = bva[j-32]; }
            val = (unsigned)f2bf(bf_) | ((unsigned)f2bf(pd_) << 16);
        }
        wsd[j*52 + kd] = val;
    }
    // wot (fp16) + rel: block 7
    if (bj == 7) {
        for (int i = tid; i < WOT_DWORDS; i += 256) {
            int col = i >> 5, kp = i & 31;
            wsd[WFB_DWORDS + i] = pkrtz(Wo[(2*kp)*32 + col], Wo[(2*kp + 1)*32 + col]);
        }
        for (int i = tid; i < 288; i += 256)
            ws[REL_OFF + i] = rel_pos[i] * LOG2E;
    }
}

// ---------------------------------------------------------------------------
// K2: fused pipeline, LDS = 32768 -> 5 blocks/CU.
//  A: stage 10x10 x-halo bf16 (p<100, ch<96 region) into xA rows (XOR-swz)
//  B: MFMA bf16 feature GEMM; wave owns 2 consecutive mt -> xa fragments
//     loaded ONCE and reused across the 6 nt tiles (33 -> 6 ds_read_b128)
//  C: scatter fp16 -> Lh[100][36]u16, Vh[100][72]u16
//  D: wave = head-pair, lane = pixel: logits read as b64 (4 q at once),
//     no-max exp2 softmax, PV fp16 pk-fma with op_sel broadcast
//  E: O fp16 [256][128B swz] -> mfma f16 x WoT -> C f32 -> LN -> store
// ---------------------------------------------------------------------------
__global__ __launch_bounds__(256, 5) void k2_attn(
    const float* __restrict__ x, const float* __restrict__ ws,
    const float* __restrict__ bo,
    const float* __restrict__ ln_g, const float* __restrict__ ln_b,
    float* __restrict__ out)
{
    __shared__ __align__(16) char smem[32768];
    // A/B : bf16 xA rows p=0..111, 256B stride, byte ^= (p&7)<<4     [0,28672)
    // C/D : fp16 Lh[100][36] @0 (7200B); fp16 Vh[100][72] @8192 (14400B)
    // E   : fp16 O[256][128B swz] then f32 C in place                [0,32768)

    const int tid = threadIdx.x;

    // XCD-aware swizzle: 2048 blocks, 8 XCDs -> each XCD one batch image
    const int flat = blockIdx.x;
    const int wg   = (flat & 7) * 256 + (flat >> 3);
    const int tx = wg & 15;
    const int ty = (wg >> 4) & 15;
    const int b  = wg >> 8;

    // ---- Phase A: 1200 jobs = 12 chunks x 100 pixels (i = kq*100 + p) ----
    #pragma unroll
    for (int it = 0; it < 5; ++it) {
        int i = tid + it*256;
        if (i < 1200) {
            int kq = (int)(((unsigned)i * 5243u) >> 19);   // i/100
            int p  = i - kq*100;
            int py = p / 10, px = p - py*10;
            int gy = ty*8 - 1 + py, gx = tx*8 - 1 + px;
            bool valid = ((unsigned)gy < 128u) && ((unsigned)gx < 128u);
            u32x4 pack = {0u, 0u, 0u, 0u};
            if (kq < 8) {
                if (valid) {
                    const float* xp = x + ((size_t)b*64 + kq*8)*HW + gy*WIDTH + gx;
                    #pragma unroll
                    for (int e = 0; e < 4; ++e)
                        pack[e] = cvtpk(xp[(size_t)(2*e)*HW], xp[(size_t)(2*e+1)*HW]);
                }
            } else if (kq == 8) {
                pack[0] = valid ? 0x00003f80u : 0x3f800000u;  // bf16 flags ch64/65
            }
            // kq 9..11 stay zero (ch 72..95 must be 0: wfb zeros x NaN-garbage hazard)
            *(u32x4*)(smem + p*256 + (((unsigned)(kq*16)) ^ (((unsigned)(p & 7)) << 4))) = pack;
        }
    }
    __syncthreads();

    const int lane = tid & 63;
    const int wv   = tid >> 6;
    const int frow = lane & 15;
    const int kseg = lane >> 4;

    // ---- Phase B: bf16 feature GEMM, xa reuse across nt ----
    const unsigned short* wfs = (const unsigned short*)ws;
    f32x4 accs[12];
    #pragma unroll
    for (int mi = 0; mi < 2; ++mi) {
        const int mt = wv*2 + mi;
        if (mt < 7) {
            const int prow = mt*16 + frow;
            const unsigned psw = ((unsigned)(prow & 7)) << 4;
            bshort8 xa0 = *(const bshort8*)(smem + prow*256 + (((unsigned)(kseg*16))       ^ psw));
            bshort8 xa1 = *(const bshort8*)(smem + prow*256 + (((unsigned)(kseg*16 + 64))  ^ psw));
            bshort8 xa2 = *(const bshort8*)(smem + prow*256 + (((unsigned)(kseg*16 + 128)) ^ psw));
            #pragma unroll
            for (int nt = 0; nt < 6; ++nt) {
                const unsigned short* wrow = wfs + (nt*16 + frow)*104 + kseg*8;
                f32x4 acc = {0.f, 0.f, 0.f, 0.f};
                acc = __builtin_amdgcn_mfma_f32_16x16x32_bf16(*(const bshort8*)(wrow),      xa0, acc, 0, 0, 0);
                acc = __builtin_amdgcn_mfma_f32_16x16x32_bf16(*(const bshort8*)(wrow + 32), xa1, acc, 0, 0, 0);
                acc = __builtin_amdgcn_mfma_f32_16x16x32_bf16(*(const bshort8*)(wrow + 64), xa2, acc, 0, 0, 0);
                accs[mi*6 + nt] = acc;
            }
        }
    }
    __syncthreads();   // xA dead

    // ---- Phase C: fp16 scatter ----
    unsigned short* Lh = (unsigned short*)smem;            // [100][36]
    unsigned short* Vh = (unsigned short*)(smem + 8192);   // [100][72]
    #pragma unroll
    for (int mi = 0; mi < 2; ++mi) {
        const int mt = wv*2 + mi;
        if (mt < 7) {
            const int p = mt*16 + frow;
            if (p < 100) {
                #pragma unroll
                for (int nt = 0; nt < 6; ++nt) {
                    const f32x4 acc = accs[mi*6 + nt];
                    u32x2 dd = { pkrtz(acc[0], acc[1]), pkrtz(acc[2], acc[3]) };
                    if (nt < 2) *(u32x2*)(Lh + p*36 + nt*16 + kseg*4) = dd;
                    else        *(u32x2*)(Vh + p*72 + (nt-2)*16 + kseg*4) = dd;
                }
            }
        }
    }
    __syncthreads();

    // ---- Phase D: wave = head-pair, lane = pixel, all 4 q ----
    const int dpy = lane >> 3, dpx = lane & 7;
    const int pbase = dpy*10 + dpx;
    const float* relw = ws + REL_OFF;

    unsigned od[32];   // packed fp16 O rows: [(q*2+hh)*4 + j]
    #pragma unroll
    for (int hh = 0; hh < 2; ++hh) {
        const int h = wv*2 + hh;
        unsigned apk[2][9];
        float s0 = 0.f, s1 = 0.f, s2 = 0.f, s3 = 0.f;
        const float* rp = relw + h*36;   // rel[h*4+q][n] = rp[q*9 + n]
        #pragma unroll
        for (int n = 0; n < 9; ++n) {
            const int off = (n/3)*10 + (n%3);
            const u32x2 L4 = *(const u32x2*)(Lh + (pbase + off)*36 + h*4);
            float e0 = exp2f(lo16f(L4[0]) + rp[n]);
            float e1 = exp2f(hi16f(L4[0]) + rp[9 + n]);
            float e2 = exp2f(lo16f(L4[1]) + rp[18 + n]);
            float e3 = exp2f(hi16f(L4[1]) + rp[27 + n]);
            s0 += e0; s1 += e1; s2 += e2; s3 += e3;
            apk[0][n] = pkrtz(e0, e1);
            apk[1][n] = pkrtz(e2, e3);
        }
        const unsigned r01 = pkrtz(__builtin_amdgcn_rcpf(s0), __builtin_amdgcn_rcpf(s1));
        const unsigned r23 = pkrtz(__builtin_amdgcn_rcpf(s2), __builtin_amdgcn_rcpf(s3));

        unsigned o16[4][4] = {{0u,0u,0u,0u},{0u,0u,0u,0u},{0u,0u,0u,0u},{0u,0u,0u,0u}};
        #pragma unroll
        for (int n = 0; n < 9; ++n) {
            const int off = (n/3)*10 + (n%3);
            const u32x4 v4 = *(const u32x4*)(Vh + (pbase + off)*72 + h*8);
            #pragma unroll
            for (int j = 0; j < 4; ++j) {
                o16[0][j] = pkfma16_lo(o16[0][j], apk[0][n], v4[j]);
                o16[1][j] = pkfma16_hi(o16[1][j], apk[0][n], v4[j]);
                o16[2][j] = pkfma16_lo(o16[2][j], apk[1][n], v4[j]);
                o16[3][j] = pkfma16_hi(o16[3][j], apk[1][n], v4[j]);
            }
        }
        #pragma unroll
        for (int j = 0; j < 4; ++j) {
            od[(0*2 + hh)*4 + j] = pkmul16_lo(o16[0][j], r01);
            od[(1*2 + hh)*4 + j] = pkmul16_hi(o16[1][j], r01);
            od[(2*2 + hh)*4 + j] = pkmul16_lo(o16[2][j], r23);
            od[(3*2 + hh)*4 + j] = pkmul16_hi(o16[3][j], r23);
        }
    }
    __syncthreads();   // Lh/Vh dead

    // O-writes: row = lane*4+q (128B rows, byte ^= ((row>>2)&7)<<4 = (lane&7)<<4)
    {
        const unsigned sw = ((unsigned)(lane & 7)) << 4;
        #pragma unroll
        for (int q = 0; q < 4; ++q) {
            const int row = lane*4 + q;
            #pragma unroll
            for (int hh = 0; hh < 2; ++hh) {
                u32x4 w4 = { od[(q*2+hh)*4+0], od[(q*2+hh)*4+1],
                             od[(q*2+hh)*4+2], od[(q*2+hh)*4+3] };
                *(u32x4*)(smem + row*128 + (((unsigned)(wv*32 + hh*16)) ^ sw)) = w4;
            }
        }
    }
    __syncthreads();   // O complete (cross-wave)

    // ---- Phase E: Wo via fp16 MFMA; wave wv owns rows [wv*64, wv*64+64) ----
    const unsigned short* wotu = (const unsigned short*)ws + WFB_DWORDS*2;
    half8 av[4][2];
    #pragma unroll
    for (int mt = 0; mt < 4; ++mt) {
        const int row = wv*64 + mt*16 + frow;
        const unsigned sw = (((unsigned)(row >> 2)) & 7u) << 4;
        #pragma unroll
        for (int ks = 0; ks < 2; ++ks)
            av[mt][ks] = __builtin_bit_cast(half8,
                *(const u32x4*)(smem + row*128 + (((unsigned)(kseg*16 + ks*64)) ^ sw)));
    }
    half8 bv_[2][2];
    #pragma unroll
    for (int nt = 0; nt < 2; ++nt) {
        const int col = nt*16 + frow;
        #pragma unroll
        for (int ks = 0; ks < 2; ++ks)
            bv_[nt][ks] = __builtin_bit_cast(half8,
                *(const u32x4*)(wotu + col*64 + kseg*8 + ks*32));
    }
    f32x4 cacc[4][2];
    #pragma unroll
    for (int mt = 0; mt < 4; ++mt)
        #pragma unroll
        for (int nt = 0; nt < 2; ++nt)
            cacc[mt][nt] = (f32x4){0.f, 0.f, 0.f, 0.f};
    #pragma unroll
    for (int ks = 0; ks < 2; ++ks)
        #pragma unroll
        for (int mt = 0; mt < 4; ++mt)
            #pragma unroll
            for (int nt = 0; nt < 2; ++nt)
                cacc[mt][nt] = __builtin_amdgcn_mfma_f32_16x16x32_f16(
                    av[mt][ks], bv_[nt][ks], cacc[mt][nt], 0, 0, 0);

    // C-write f32 into own 8KB slice (only own wave reads)
    #pragma unroll
    for (int mt = 0; mt < 4; ++mt)
        #pragma unroll
        for (int nt = 0; nt < 2; ++nt)
            #pragma unroll
            for (int r = 0; r < 4; ++r) {
                const int row = wv*64 + mt*16 + kseg*4 + r;
                const int col = nt*16 + frow;
                *(float*)(smem + row*128
                    + (((unsigned)(col*4)) ^ ((((unsigned)(row >> 2)) & 7u) << 4)))
                    = cacc[mt][nt][r];
            }
    asm volatile("s_waitcnt lgkmcnt(0)" ::: "memory");

    // C-read own row (= tid), add bo, LN, pixel-shuffle store
    float cv[32];
    {
        const unsigned sw = (((unsigned)(tid >> 2)) & 7u) << 4;
        #pragma unroll
        for (int j = 0; j < 8; ++j) {
            const f32x4 c4 = *(const f32x4*)(smem + tid*128 + (((unsigned)(j*16)) ^ sw));
            cv[j*4+0] = c4[0]; cv[j*4+1] = c4[1]; cv[j*4+2] = c4[2]; cv[j*4+3] = c4[3];
        }
    }
    float mu = 0.f;
    #pragma unroll
    for (int oc = 0; oc < 32; ++oc) { cv[oc] += bo[oc]; mu += cv[oc]; }
    mu *= (1.f/32.f);
    float var = 0.f;
    #pragma unroll
    for (int oc = 0; oc < 32; ++oc) { float d = cv[oc] - mu; var += d*d; }
    var *= (1.f/32.f);
    const float rstd = rsqrtf(var + 1e-5f);

    const int q   = tid & 3;
    const int pix = tid >> 2;
    const int gy = ty*8 + (pix >> 3), gx = tx*8 + (pix & 7);
    const int Y = gy*2 + (q >> 1), X = gx*2 + (q & 1);
    float* op = out + (((size_t)b*32)*256 + Y)*256 + X;
    #pragma unroll
    for (int oc = 0; oc < 32; ++oc) {
        float v = (cv[oc] - mu) * rstd * ln_g[oc] + ln_b[oc];
        op[(size_t)oc * 65536] = v;
    }
}

// ---------------------------------------------------------------------------
extern "C" void kernel_launch(void* const* d_in, const int* in_sizes, int n_in,
                              void* d_out, int out_size, void* d_ws, size_t ws_size,
                              hipStream_t stream)
{
    const float* x        = (const float*)d_in[0];
    const float* up_query = (const float*)d_in[1];
    const float* Wk  = (const float*)d_in[2];
    const float* bk  = (const float*)d_in[3];
    const float* Wv  = (const float*)d_in[4];
    const float* bv  = (const float*)d_in[5];
    const float* Wq  = (const float*)d_in[6];
    const float* bq  = (const float*)d_in[7];
    const float* Wka = (const float*)d_in[8];
    const float* bka = (const float*)d_in[9];
    const float* Wva = (const float*)d_in[10];
    const float* bva = (const float*)d_in[11];
    const float* Wo  = (const float*)d_in[12];
    const float* bo  = (const float*)d_in[13];
    const float* rel_pos = (const float*)d_in[14];
    const float* ln_g = (const float*)d_in[15];
    const float* ln_b = (const float*)d_in[16];

    float* ws  = (float*)d_ws;
    float* out = (float*)d_out;

    if (ws_size < (size_t)(REL_OFF + 288) * 4) return;

    k0_fuse<<<8, 256, 0, stream>>>(up_query, Wk, bk, Wv, bv, Wq, bq,
                                   Wka, bka, Wva, bva, Wo, rel_pos, ws);
    k2_attn<<<2048, 256, 0, stream>>>(x, ws, bo, ln_g, ln_b, out);
}